// Round 8
// baseline (313.213 us; speedup 1.0000x reference)
//
#include <hip/hip_runtime.h>

#define MM 32
#define LH 128
#define NSTEPS 15          // K-1
#define SSTR 136
#define NBLK 256           // 2 own rows + 2 halo rows per block, 512 threads
#define FSTR 32
#define SIDX(row,pxi,ch) (((row)*34 + (pxi))*SSTR + (ch))

typedef __bf16  bf16x8  __attribute__((ext_vector_type(8)));
typedef float   floatx4 __attribute__((ext_vector_type(4)));
typedef unsigned long long ull;

#define L2E 1.4426950408889634f

__device__ __forceinline__ float ex2(float x){
#if __has_builtin(__builtin_amdgcn_exp2f)
  return __builtin_amdgcn_exp2f(x);
#else
  float r; asm volatile("v_exp_f32 %0, %1\n\ts_nop 0" : "=v"(r) : "v"(x)); return r;
#endif
}
__device__ __forceinline__ float frcp(float x){ return __builtin_amdgcn_rcpf(x); }

__device__ __forceinline__ unsigned short cvt_bf16(float x){
  __bf16 b = (__bf16)x; unsigned short u; __builtin_memcpy(&u, &b, 2); return u;
}
__device__ __forceinline__ float bf2f(unsigned short u){
  union { unsigned u2; float f; } v; v.u2 = ((unsigned)u) << 16;
  return v.f;
}

// relaxed agent-scope ops (cross-XCD coherent point) — the proven transport
__device__ __forceinline__ void st_dev(ull* p, ull v){
  __hip_atomic_store(p, v, __ATOMIC_RELAXED, __HIP_MEMORY_SCOPE_AGENT);
}
__device__ __forceinline__ ull ld_dev(ull* p){
  return __hip_atomic_load(p, __ATOMIC_RELAXED, __HIP_MEMORY_SCOPE_AGENT);
}
// poison-safe relaxed spin (0xAAAAAAAA == far behind under signed diff)
__device__ __forceinline__ void wait_flag(int* f, int target){
  while ((int)(__hip_atomic_load(f, __ATOMIC_RELAXED, __HIP_MEMORY_SCOPE_AGENT) - target) < 0){
    __builtin_amdgcn_s_sleep(1);
  }
}
__device__ __forceinline__ void set_flag(int* f, int v){
  __hip_atomic_store(f, v, __ATOMIC_RELAXED, __HIP_MEMORY_SCOPE_AGENT);
}

// HALO-1 scheme. Block p (pair = blk&15, y0 = pair*2) maintains LSTM state
// for rows A=y0-1, B=y0, C=y0+1, D=y0+2 (A,D computed REDUNDANTLY,
// bit-identical to the neighbors that own them: identical MFMA sequences and
// identical above+center+below fp32 add order). Imports are only the conv
// partials at the halo EDGES: row A needs P(row y0-2, ky=0) (= up-neighbor's
// own-row product), row D needs P(row y0+3, ky=2). Exports are produced from
// OWN rows at step start (no import dependency); imports are consumed only in
// the last phase (halo epilogue) — the fabric RT hides under the whole step.
//
// expbuf[parity][blk][64]: slots 0..31 = UP-export P(C,ky=2) (consumed by
// p-1's halo-D), 32..63 = DOWN-export P(B,ky=0) (consumed by p+1's halo-A).
// Entry = (tag=2+s)<<32 | f32 bits. Parity double-buffer race-free: producer
// overwrites parity at s+2 only after its s+1 halo phase, which requires the
// consumer past its step-s read.
__global__ __launch_bounds__(512) void k_mega(
    const float* __restrict__ mp,   const float* __restrict__ gl,
    const float* __restrict__ W_hid,const float* __restrict__ b_hid,
    const float* __restrict__ W_h0, const float* __restrict__ b_h0,
    const float* __restrict__ W_c0, const float* __restrict__ b_c0,
    const float* __restrict__ Wf,   const float* __restrict__ bfs,
    const float* __restrict__ wih,  const float* __restrict__ bih,
    const float* __restrict__ Whh,  const float* __restrict__ bhh,
    const float* __restrict__ wpol,
    unsigned short* __restrict__ wc0, unsigned short* __restrict__ wc1,
    unsigned short* __restrict__ whhf, float* __restrict__ bsum,
    unsigned short* __restrict__ wfbF,
    ull* __restrict__ expbuf,
    int* __restrict__ flags, float* __restrict__ out)
{
  // sH rows 0..5: prologue = hid rows y0-2..y0+3; steps: rows 1..4 = A..D
  __shared__ __attribute__((aligned(16))) unsigned short sH[6*34*SSTR]; // 55.5 KB
  __shared__ float sCv[10][3][36];    // per-product tap scratch
  __shared__ float sOwn[4][3][32];    // [out row A..D][above,center,below][x]
  __shared__ float sImp[2][32];       // imported edge partials (for A, for D)

  int t = threadIdx.x, blk = blockIdx.x;
  int pair = blk & 15, b = blk >> 4;
  int y0 = pair*2;
  int nU = blk - 1, nD = blk + 1;
  int wave = t >> 6, l = t & 63, m16 = l & 15, quad = l >> 4;
  bool hasU = (pair > 0), hasD = (pair < 15);
  int ch = wave*16 + m16;             // this wave's 16-ch tile

  // ---- phase P: weight prep into fragment-linear bf16 -------------------
  // W_hh rows prescaled per-gate by SC[q] (folds log2e into exp2 args).
  for (int c = blk*512 + t; c < 91904; c += NBLK*512){
    if (c < 73728){
      int which = (c >= 36864) ? 1 : 0;
      int cc = which ? c - 36864 : c;
      int i2 = cc*4, frag = i2 >> 9, rem = i2 & 511, ll = rem >> 3, e0 = rem & 7;
      int kk = frag >> 5, ct = (frag >> 2) & 7, kc = frag & 3;
      int co = ct*16 + (ll & 15), ci0 = kc*32 + ((ll >> 4) << 3) + e0;
      const float* src = which ? W_c0 : W_h0;
      ull v = 0;
      #pragma unroll
      for (int j=0;j<4;j++) v |= (ull)cvt_bf16(src[(kk<<14) + (ci0+j)*128 + co]) << (16*j);
      st_dev((ull*)(which ? wc1 : wc0) + cc, v);
    } else if (c < 90112){
      int cc = c - 73728;
      int i2 = cc*4, frag = i2 >> 9, rem = i2 & 511, ll = rem >> 3, e0 = rem & 7;
      int q = frag >> 5, ct = (frag >> 2) & 7, kc = frag & 3;
      float scq = (q == 2) ? (2.f*L2E) : (-L2E);
      int rw = q*128 + ct*16 + (ll & 15), col = kc*32 + ((ll >> 4) << 3) + e0;
      const float* s4 = Whh + rw*128 + col;
      ull v = 0;
      #pragma unroll
      for (int j=0;j<4;j++) v |= (ull)cvt_bf16(s4[j]*scq) << (16*j);
      st_dev((ull*)whhf + cc, v);
    } else if (c < 90368){
      int cc = c - 90112; int j = cc*2;
      union { float f[2]; ull u; } pv;
      pv.f[0] = bih[j] + bhh[j]; pv.f[1] = bih[j+1] + bhh[j+1];
      st_dev((ull*)bsum + cc, pv.u);
    } else {
      // wf B-fragments: frag = ky*4+kc; cols 0..2 = Wf taps (kx), rest zero
      int cc = c - 90368;
      int i2 = cc*4, frag = i2 >> 9, rem = i2 & 511, ll = rem >> 3, e0 = rem & 7;
      int ky = frag >> 2, kc = frag & 3;
      int n = ll & 15, k0 = kc*32 + ((ll >> 4) << 3) + e0;
      ull v = 0;
      if (n < 3){
        #pragma unroll
        for (int j=0;j<4;j++) v |= (ull)cvt_bf16(Wf[(ky*3 + n)*128 + k0 + j]) << (16*j);
      }
      st_dev((ull*)wfbF + cc, v);
    }
  }
  // zero own export slots (both parities): poll tags always defined
  if (t < 128){
    int p = t >> 6, w2 = t & 63;
    st_dev(expbuf + ((size_t)p*NBLK + blk)*64 + w2, 0);
  }
  __syncthreads();                              // vmcnt drained
  if (t == 0) set_flag(&flags[blk*FSTR], 1);

  // ---- phase H: hid rows y0-2..y0+3 computed redundantly into LDS -------
  {
    int hch = t & 127, g = t >> 7;              // 4 groups over 6 rows
    float wz0[9], wz1[9];
    #pragma unroll
    for (int kk=0;kk<9;kk++){ wz0[kk] = W_hid[(kk*2)*LH + hch];
                              wz1[kk] = W_hid[(kk*2+1)*LH + hch]; }
    float bh = b_hid[hch];
    for (int rr = g; rr < 6; rr += 4){
      int yi = y0 - 2 + rr;
      bool valid = (yi >= 0 && yi < MM);
      for (int x = 0; x < MM; x++){
        float acc2 = 0.f;
        if (valid){
          acc2 = bh;
          #pragma unroll
          for (int ky=0; ky<3; ky++){
            int yy = yi + ky - 1; if (yy < 0 || yy >= MM) continue;
            #pragma unroll
            for (int kx=0; kx<3; kx++){
              int xx = x + kx - 1; if (xx < 0 || xx >= MM) continue;
              int gi = (b*MM + yy)*MM + xx;
              acc2 += mp[gi]*wz0[ky*3+kx] + gl[gi]*wz1[ky*3+kx];
            }
          }
        }
        sH[SIDX(rr, x+1, hch)] = cvt_bf16(acc2);
      }
    }
  }
  if (t < 384){   // zero x-halo columns, rows 0..5
    int k = t >> 6, col = ((t >> 5) & 1) ? 33 : 0, c4 = t & 31;
    *(ull*)&sH[SIDX(k, col, c4*4)] = 0;
  }
  // zero the two never-written tap-scratch entries per product (once)
  if (t < 10){ sCv[t][0][32] = 0.f; sCv[t][2][1] = 0.f; }
  // grid sync: only prepper blocks' flags (blk<=179)
  if (t < 180) wait_flag(&flags[t*FSTR], 1);
  __syncthreads();

  // ---- h0 & c0 convs: rows A..D (128 px), this wave's 16 out-ch ---------
  float c_reg[8][4];        // [mt 0..7 = (row A..D, half)][r]
  {
    floatx4 acch[8], accc[8];
    #pragma unroll
    for (int mt=0;mt<8;mt++){ acch[mt] = (floatx4){0.f,0.f,0.f,0.f};
                              accc[mt] = (floatx4){0.f,0.f,0.f,0.f}; }
    #pragma unroll
    for (int kk=0; kk<9; kk++){
      int ky = kk/3, kx = kk%3;
      #pragma unroll
      for (int kc=0; kc<4; kc++){
        int frag = ((kk*8 + wave)*4 + kc);
        bf16x8 b0 = *(const bf16x8*)(wc0 + (frag << 9) + l*8);
        bf16x8 b1 = *(const bf16x8*)(wc1 + (frag << 9) + l*8);
        #pragma unroll
        for (int mt=0; mt<8; mt++){
          bf16x8 a = *(const bf16x8*)&sH[SIDX((mt>>1)+ky, m16 + (mt&1)*16 + kx, kc*32 + quad*8)];
          acch[mt] = __builtin_amdgcn_mfma_f32_16x16x32_bf16(a, b0, acch[mt], 0,0,0);
          accc[mt] = __builtin_amdgcn_mfma_f32_16x16x32_bf16(a, b1, accc[mt], 0,0,0);
        }
      }
    }
    __syncthreads();                      // all conv reads done
    float bh = b_h0[ch], bc = b_c0[ch];
    #pragma unroll
    for (int mt=0; mt<8; mt++){
      bool dead = (mt < 2 && !hasU) || (mt >= 6 && !hasD);
      #pragma unroll
      for (int r=0; r<4; r++){
        int x = (mt&1)*16 + quad*4 + r;
        float hv = dead ? 0.f : (acch[mt][r] + bh);
        c_reg[mt][r] = dead ? 0.f : (accc[mt][r] + bc);
        sH[SIDX(1+(mt>>1), x+1, ch)] = cvt_bf16(hv);
      }
    }
  }
  __syncthreads();                        // h0 for A..D in LDS rows 1..4

  float wv[4], bs[4];
  #pragma unroll
  for (int q=0;q<4;q++){
    float scq = (q == 2) ? (2.f*L2E) : (-L2E);
    int g = q*128 + ch;
    wv[q] = wih[g]*scq; bs[q] = bsum[g]*scq;
  }
  float bf0 = bfs[0];

  // ---- 15 LSTM steps ----------------------------------------------------
  for (int s = 0; s < NSTEPS; s++){
    int cur = s & 1;
    unsigned tgt = (unsigned)(2 + s);

    // speculative import loads at step start (w5: up-edge, w6: down-edge)
    ull specv = 0; ull* pP = nullptr;
    if (wave == 5 && hasU && l < 32){
      pP = expbuf + ((size_t)cur*NBLK + nU)*64 + 32 + l;  // their DOWN-export
      specv = ld_dev(pP);
    } else if (wave == 6 && hasD && l < 32){
      pP = expbuf + ((size_t)cur*NBLK + nD)*64 + l;       // their UP-export
      specv = ld_dev(pP);
    }

    // P1 (waves 0-4): conv products P(R,ky), 2 per wave. Products feeding
    // exports publish IMMEDIATELY (produced from own rows, no import dep).
    // descriptor: R | ky<<2 | dstRow<<4 | dstPart<<6 | pub<<8 (1=up,2=down)
    if (wave < 5){
      int d0, d1;
      switch (wave){
        case 0:  d0 = 1|(1<<2)|(1<<4)|(1<<6);         d1 = 2|(1<<2)|(2<<4)|(1<<6); break;
        case 1:  d0 = 1|(0<<2)|(2<<4)|(0<<6)|(2<<8);  d1 = 0|(0<<2)|(1<<4)|(0<<6); break;
        case 2:  d0 = 2|(2<<2)|(1<<4)|(2<<6)|(1<<8);  d1 = 3|(2<<2)|(2<<4)|(2<<6); break;
        case 3:  d0 = 0|(1<<2)|(0<<4)|(1<<6);         d1 = 1|(2<<2)|(0<<4)|(2<<6); break;
        default: d0 = 2|(0<<2)|(3<<4)|(0<<6);         d1 = 3|(1<<2)|(3<<4)|(1<<6); break;
      }
      #pragma unroll
      for (int wp = 0; wp < 2; wp++){
        int dsc = wp ? d1 : d0;
        int R = dsc & 3, ky = (dsc>>2)&3, dR = (dsc>>4)&3, dP = (dsc>>6)&3, pub = (dsc>>8)&3;
        int slot = wave*2 + wp;
        floatx4 q0 = (floatx4){0.f,0.f,0.f,0.f};
        floatx4 q1 = (floatx4){0.f,0.f,0.f,0.f};
        #pragma unroll
        for (int kc=0;kc<4;kc++){
          bf16x8 wf = *(const bf16x8*)(wfbF + (((ky*4 + kc) << 9) + l*8));
          bf16x8 aL = *(const bf16x8*)&sH[SIDX(1+R, m16 + 1,  kc*32 + quad*8)];
          bf16x8 aR = *(const bf16x8*)&sH[SIDX(1+R, m16 + 17, kc*32 + quad*8)];
          q0 = __builtin_amdgcn_mfma_f32_16x16x32_bf16(aL, wf, q0, 0,0,0);
          q1 = __builtin_amdgcn_mfma_f32_16x16x32_bf16(aR, wf, q1, 0,0,0);
        }
        if (m16 < 3){
          #pragma unroll
          for (int r=0;r<4;r++){
            sCv[slot][m16][quad*4 + r + m16]      = q0[r];
            sCv[slot][m16][16 + quad*4 + r + m16] = q1[r];
          }
        }
        __asm__ __volatile__("" ::: "memory");  // same-wave DS in-order
        if (l < 32){
          float v = sCv[slot][0][l+1] + sCv[slot][1][l+1] + sCv[slot][2][l+1];
          if (pub){
            bool okp = (pub == 2) ? hasD : hasU;
            if (okp){
              union { float f; unsigned u; } pv; pv.f = v;
              st_dev(expbuf + ((size_t)cur*NBLK + blk)*64 + ((pub == 2) ? 32 : 0) + l,
                     ((ull)tgt << 32) | (ull)pv.u);
            }
          }
          sOwn[dR][dP][l] = v;
        }
      }
    }

    // P2: gates GEMM own rows B,C (LDS rows 2,3); B streamed from L2 whhf
    ull wa = (ull)whhf;
    asm volatile("" : "+v"(wa));
    const unsigned short* wp8 = (const unsigned short*)wa;
    floatx4 accO[4][4];
    #pragma unroll
    for (int m=0;m<4;m++)
      #pragma unroll
      for (int q=0;q<4;q++) accO[m][q] = (floatx4){0.f,0.f,0.f,0.f};
    #pragma unroll
    for (int kc=0; kc<4; kc++){
      bf16x8 a0 = *(const bf16x8*)&sH[SIDX(2, m16 + 1,  kc*32 + quad*8)];
      bf16x8 a1 = *(const bf16x8*)&sH[SIDX(2, m16 + 17, kc*32 + quad*8)];
      bf16x8 a2 = *(const bf16x8*)&sH[SIDX(3, m16 + 1,  kc*32 + quad*8)];
      bf16x8 a3 = *(const bf16x8*)&sH[SIDX(3, m16 + 17, kc*32 + quad*8)];
      #pragma unroll
      for (int q=0; q<4; q++){
        bf16x8 bq = *(const bf16x8*)(wp8 + ((q*32 + wave*4 + kc) << 9) + l*8);
        accO[0][q] = __builtin_amdgcn_mfma_f32_16x16x32_bf16(a0, bq, accO[0][q], 0,0,0);
        accO[1][q] = __builtin_amdgcn_mfma_f32_16x16x32_bf16(a1, bq, accO[1][q], 0,0,0);
        accO[2][q] = __builtin_amdgcn_mfma_f32_16x16x32_bf16(a2, bq, accO[2][q], 0,0,0);
        accO[3][q] = __builtin_amdgcn_mfma_f32_16x16x32_bf16(a3, bq, accO[3][q], 0,0,0);
      }
    }
    __syncthreads();                      // B1: sOwn complete, h_s reads of B,C done

    // E1: epilogue own rows B,C -> h_{s+1} into LDS rows 2,3 (no import dep)
    #pragma unroll
    for (int m=0; m<4; m++){
      int mt = 2 + m, rw = 1 + (m>>1);
      #pragma unroll
      for (int r=0; r<4; r++){
        int x = (m&1)*16 + quad*4 + r;
        float iv = ((bf0 + sOwn[rw][0][x]) + sOwn[rw][1][x]) + sOwn[rw][2][x];
        float p0 = accO[m][0][r] + iv*wv[0] + bs[0];
        float p1 = accO[m][1][r] + iv*wv[1] + bs[1];
        float p2 = accO[m][2][r] + iv*wv[2] + bs[2];
        float p3 = accO[m][3][r] + iv*wv[3] + bs[3];
        float ig = frcp(1.f + ex2(p0));
        float fg = frcp(1.f + ex2(p1));
        float gg = 1.f - 2.f*frcp(1.f + ex2(p2));
        float og = frcp(1.f + ex2(p3));
        float cn = fg*c_reg[mt][r] + ig*gg;
        c_reg[mt][r] = cn;
        float th = 1.f - 2.f*frcp(1.f + ex2((2.f*L2E)*cn));
        sH[SIDX(1+rw, x+1, ch)] = cvt_bf16(og*th);
      }
    }

    // P3: gates GEMM halo rows A,D (LDS rows 1,4 — still h_s)
    floatx4 accH[4][4];
    #pragma unroll
    for (int m=0;m<4;m++)
      #pragma unroll
      for (int q=0;q<4;q++) accH[m][q] = (floatx4){0.f,0.f,0.f,0.f};
    #pragma unroll
    for (int kc=0; kc<4; kc++){
      bf16x8 a0 = *(const bf16x8*)&sH[SIDX(1, m16 + 1,  kc*32 + quad*8)];
      bf16x8 a1 = *(const bf16x8*)&sH[SIDX(1, m16 + 17, kc*32 + quad*8)];
      bf16x8 a2 = *(const bf16x8*)&sH[SIDX(4, m16 + 1,  kc*32 + quad*8)];
      bf16x8 a3 = *(const bf16x8*)&sH[SIDX(4, m16 + 17, kc*32 + quad*8)];
      #pragma unroll
      for (int q=0; q<4; q++){
        bf16x8 bq = *(const bf16x8*)(wp8 + ((q*32 + wave*4 + kc) << 9) + l*8);
        accH[0][q] = __builtin_amdgcn_mfma_f32_16x16x32_bf16(a0, bq, accH[0][q], 0,0,0);
        accH[1][q] = __builtin_amdgcn_mfma_f32_16x16x32_bf16(a1, bq, accH[1][q], 0,0,0);
        accH[2][q] = __builtin_amdgcn_mfma_f32_16x16x32_bf16(a2, bq, accH[2][q], 0,0,0);
        accH[3][q] = __builtin_amdgcn_mfma_f32_16x16x32_bf16(a3, bq, accH[3][q], 0,0,0);
      }
    }

    // import check/poll (w5/w6) — export has been in flight the whole step
    if (pP){
      ull val = specv;
      if ((int)((unsigned)(val >> 32) - tgt) < 0){
        ull c0 = ld_dev(pP), c1 = ld_dev(pP);
        while ((int)((unsigned)(c0 >> 32) - tgt) < 0){ c0 = c1; c1 = ld_dev(pP); }
        val = c0;
      }
      union { unsigned u; float f; } pv; pv.u = (unsigned)val;
      sImp[(wave == 5) ? 0 : 1][l] = pv.f;
    }
    __syncthreads();                      // B3a: sImp ready, h_s(A,D) reads done

    // E2: halo epilogue rows A,D -> h_{s+1} into LDS rows 1,4
    #pragma unroll
    for (int m=0; m<4; m++){
      int mt = (m < 2) ? m : (4 + m);     // 0,1,6,7
      int rw = (m < 2) ? 0 : 3;
      if ((rw == 0) ? hasU : hasD){
        #pragma unroll
        for (int r=0; r<4; r++){
          int x = (m&1)*16 + quad*4 + r;
          float pa = (rw == 0) ? sImp[0][x] : sOwn[3][0][x];
          float pc = sOwn[rw][1][x];
          float pb = (rw == 0) ? sOwn[0][2][x] : sImp[1][x];
          float iv = ((bf0 + pa) + pc) + pb;
          float p0 = accH[m][0][r] + iv*wv[0] + bs[0];
          float p1 = accH[m][1][r] + iv*wv[1] + bs[1];
          float p2 = accH[m][2][r] + iv*wv[2] + bs[2];
          float p3 = accH[m][3][r] + iv*wv[3] + bs[3];
          float ig = frcp(1.f + ex2(p0));
          float fg = frcp(1.f + ex2(p1));
          float gg = 1.f - 2.f*frcp(1.f + ex2(p2));
          float og = frcp(1.f + ex2(p3));
          float cn = fg*c_reg[mt][r] + ig*gg;
          c_reg[mt][r] = cn;
          float th = 1.f - 2.f*frcp(1.f + ex2((2.f*L2E)*cn));
          sH[SIDX((rw == 0) ? 1 : 4, x+1, ch)] = cvt_bf16(og*th);
        }
      }
    }
    __syncthreads();                      // B3b: all h_{s+1} visible in LDS
  }

  // ---- policy: logits + 4-way softmax from own rows (LDS rows 2,3) ------
  {
    int px = t >> 3, s8 = t & 7;
    int base = SIDX(2+(px>>5), (px&31)+1, s8*16);
    uint4 h0v = *(const uint4*)&sH[base];
    uint4 h1v = *(const uint4*)&sH[base + 8];
    float la[4] = {0.f,0.f,0.f,0.f};
    const unsigned short* hu = (const unsigned short*)&h0v;
    #pragma unroll
    for (int e=0;e<8;e++){
      int c = s8*16 + e; float hv2 = bf2f(hu[e]);
      const float* w4 = wpol + c*4;
      la[0]+=hv2*w4[0]; la[1]+=hv2*w4[1]; la[2]+=hv2*w4[2]; la[3]+=hv2*w4[3];
    }
    hu = (const unsigned short*)&h1v;
    #pragma unroll
    for (int e=0;e<8;e++){
      int c = s8*16 + 8 + e; float hv2 = bf2f(hu[e]);
      const float* w4 = wpol + c*4;
      la[0]+=hv2*w4[0]; la[1]+=hv2*w4[1]; la[2]+=hv2*w4[2]; la[3]+=hv2*w4[3];
    }
    #pragma unroll
    for (int a=0;a<4;a++){
      la[a] += __shfl_xor(la[a], 1, 64);
      la[a] += __shfl_xor(la[a], 2, 64);
      la[a] += __shfl_xor(la[a], 4, 64);
    }
    if (s8 == 0){
      int y = y0 + (px>>5), x = px & 31;
      float m = fmaxf(fmaxf(la[0],la[1]),fmaxf(la[2],la[3]));
      float e[4]; float sum = 0.f;
      #pragma unroll
      for (int a=0;a<4;a++){ e[a]=__expf(la[a]-m); sum+=e[a]; }
      float inv = frcp(sum);
      #pragma unroll
      for (int a=0;a<4;a++){
        int o = ((b*4 + a)*MM + y)*MM + x;
        out[o] = la[a];
        out[65536 + o] = e[a]*inv;
      }
    }
  }
}

extern "C" void kernel_launch(void* const* d_in, const int* in_sizes, int n_in,
                              void* d_out, int out_size, void* d_ws, size_t ws_size,
                              hipStream_t stream){
  const float* mp    = (const float*)d_in[0];
  const float* gl    = (const float*)d_in[1];
  const float* W_hid = (const float*)d_in[2];
  const float* b_hid = (const float*)d_in[3];
  const float* W_h0  = (const float*)d_in[4];
  const float* b_h0  = (const float*)d_in[5];
  const float* W_c0  = (const float*)d_in[6];
  const float* b_c0  = (const float*)d_in[7];
  const float* W_f   = (const float*)d_in[8];
  const float* b_f   = (const float*)d_in[9];
  const float* W_ih  = (const float*)d_in[10];
  const float* b_ih  = (const float*)d_in[11];
  const float* W_hh  = (const float*)d_in[12];
  const float* b_hh  = (const float*)d_in[13];
  const float* W_pol = (const float*)d_in[14];
  float* out = (float*)d_out;

  char* ws = (char*)d_ws;
  unsigned short* whhf  = (unsigned short*)ws;                     // 128 KB
  float*          bsum  = (float*)(ws + (128<<10));                // 4 KB
  unsigned short* wc0   = (unsigned short*)(ws + (132<<10));       // 288 KB
  unsigned short* wc1   = (unsigned short*)(ws + (420<<10));       // 288 KB
  unsigned short* wfbF  = (unsigned short*)(ws + (708<<10));       // 12 KB
  int*            flags = (int*)(ws + (720<<10));                  // 64 KB
  ull*            expbuf= (ull*)(ws + (784<<10));                  // 256 KB

  k_mega<<<NBLK, 512, 0, stream>>>(
      mp, gl, W_hid, b_hid, W_h0, b_h0, W_c0, b_c0, W_f, b_f,
      W_ih, b_ih, W_hh, b_hh, W_pol,
      wc0, wc1, whhf, bsum, wfbF, expbuf, flags, out);
}

// Round 9
// 312.940 us; speedup vs baseline: 1.0009x; 1.0009x over previous
//
#include <hip/hip_runtime.h>

#define MM 32
#define LH 128
#define NSTEPS 15          // K-1
#define SSTR 136
#define NBLK 256           // 2 own rows + 2 halo rows per block, 512 threads
#define FSTR 32
#define SIDX(row,pxi,ch) (((row)*34 + (pxi))*SSTR + (ch))

typedef __bf16  bf16x8  __attribute__((ext_vector_type(8)));
typedef float   floatx4 __attribute__((ext_vector_type(4)));
typedef unsigned long long ull;

#define L2E 1.4426950408889634f

__device__ __forceinline__ float ex2(float x){
#if __has_builtin(__builtin_amdgcn_exp2f)
  return __builtin_amdgcn_exp2f(x);
#else
  float r; asm volatile("v_exp_f32 %0, %1\n\ts_nop 0" : "=v"(r) : "v"(x)); return r;
#endif
}
__device__ __forceinline__ float frcp(float x){ return __builtin_amdgcn_rcpf(x); }

__device__ __forceinline__ unsigned short cvt_bf16(float x){
  __bf16 b = (__bf16)x; unsigned short u; __builtin_memcpy(&u, &b, 2); return u;
}
__device__ __forceinline__ float bf2f(unsigned short u){
  union { unsigned u2; float f; } v; v.u2 = ((unsigned)u) << 16;
  return v.f;
}

// relaxed agent-scope ops (cross-XCD coherent point) — the proven transport
__device__ __forceinline__ void st_dev(ull* p, ull v){
  __hip_atomic_store(p, v, __ATOMIC_RELAXED, __HIP_MEMORY_SCOPE_AGENT);
}
__device__ __forceinline__ ull ld_dev(ull* p){
  return __hip_atomic_load(p, __ATOMIC_RELAXED, __HIP_MEMORY_SCOPE_AGENT);
}
// poison-safe relaxed spin (0xAAAAAAAA == far behind under signed diff)
__device__ __forceinline__ void wait_flag(int* f, int target){
  while ((int)(__hip_atomic_load(f, __ATOMIC_RELAXED, __HIP_MEMORY_SCOPE_AGENT) - target) < 0){
    __builtin_amdgcn_s_sleep(1);
  }
}
__device__ __forceinline__ void set_flag(int* f, int v){
  __hip_atomic_store(f, v, __ATOMIC_RELAXED, __HIP_MEMORY_SCOPE_AGENT);
}

// HALO-1 scheme (R7, spill-fixed). Block p (pair = blk&15, y0 = pair*2)
// maintains LSTM state for rows A=y0-1, B=y0, C=y0+1, D=y0+2 (A,D computed
// REDUNDANTLY, bit-identical to the owning neighbors: identical MFMA
// sequences and identical above+center+below fp32 add order). Imports are
// only the conv partials at the halo EDGES (rows y0-2, y0+3). Exports are
// produced from OWN rows at step start (no import dependency); imports are
// consumed only in the final halo-epilogue phase — the fabric RT hides under
// the whole step's compute.
//
// expbuf[parity][blk][64]: slots 0..31 = UP-export P(C,ky=2) (consumed by
// p-1's halo-D), 32..63 = DOWN-export P(B,ky=0) (consumed by p+1's halo-A).
// Entry = (tag=2+s)<<32 | f32 bits. Parity double-buffer race-free.
//
// __launch_bounds__(512, 1): 256-VGPR budget — REQUIRED. R7's (512) default
// capped VGPR at 128 and spilled the accumulators to scratch (FETCH/WRITE
// exploded to 83/94 MB, 253 us). Single reused acc[4][4] (accO dies at E1
// before accH is born at P3) keeps peak live regs ~140.
__global__ __launch_bounds__(512, 1) void k_mega(
    const float* __restrict__ mp,   const float* __restrict__ gl,
    const float* __restrict__ W_hid,const float* __restrict__ b_hid,
    const float* __restrict__ W_h0, const float* __restrict__ b_h0,
    const float* __restrict__ W_c0, const float* __restrict__ b_c0,
    const float* __restrict__ Wf,   const float* __restrict__ bfs,
    const float* __restrict__ wih,  const float* __restrict__ bih,
    const float* __restrict__ Whh,  const float* __restrict__ bhh,
    const float* __restrict__ wpol,
    unsigned short* __restrict__ wc0, unsigned short* __restrict__ wc1,
    unsigned short* __restrict__ whhf, float* __restrict__ bsum,
    unsigned short* __restrict__ wfbF,
    ull* __restrict__ expbuf,
    int* __restrict__ flags, float* __restrict__ out)
{
  // sH rows 0..5: prologue = hid rows y0-2..y0+3; steps: rows 1..4 = A..D
  __shared__ __attribute__((aligned(16))) unsigned short sH[6*34*SSTR]; // 55.5 KB
  __shared__ float sCv[10][3][36];    // per-product tap scratch
  __shared__ float sOwn[4][3][32];    // [out row A..D][above,center,below][x]
  __shared__ float sImp[2][32];       // imported edge partials (for A, for D)

  int t = threadIdx.x, blk = blockIdx.x;
  int pair = blk & 15, b = blk >> 4;
  int y0 = pair*2;
  int nU = blk - 1, nD = blk + 1;
  int wave = t >> 6, l = t & 63, m16 = l & 15, quad = l >> 4;
  bool hasU = (pair > 0), hasD = (pair < 15);
  int ch = wave*16 + m16;             // this wave's 16-ch tile

  // ---- phase P: weight prep into fragment-linear bf16 -------------------
  // W_hh rows prescaled per-gate by SC[q] (folds log2e into exp2 args).
  for (int c = blk*512 + t; c < 91904; c += NBLK*512){
    if (c < 73728){
      int which = (c >= 36864) ? 1 : 0;
      int cc = which ? c - 36864 : c;
      int i2 = cc*4, frag = i2 >> 9, rem = i2 & 511, ll = rem >> 3, e0 = rem & 7;
      int kk = frag >> 5, ct = (frag >> 2) & 7, kc = frag & 3;
      int co = ct*16 + (ll & 15), ci0 = kc*32 + ((ll >> 4) << 3) + e0;
      const float* src = which ? W_c0 : W_h0;
      ull v = 0;
      #pragma unroll
      for (int j=0;j<4;j++) v |= (ull)cvt_bf16(src[(kk<<14) + (ci0+j)*128 + co]) << (16*j);
      st_dev((ull*)(which ? wc1 : wc0) + cc, v);
    } else if (c < 90112){
      int cc = c - 73728;
      int i2 = cc*4, frag = i2 >> 9, rem = i2 & 511, ll = rem >> 3, e0 = rem & 7;
      int q = frag >> 5, ct = (frag >> 2) & 7, kc = frag & 3;
      float scq = (q == 2) ? (2.f*L2E) : (-L2E);
      int rw = q*128 + ct*16 + (ll & 15), col = kc*32 + ((ll >> 4) << 3) + e0;
      const float* s4 = Whh + rw*128 + col;
      ull v = 0;
      #pragma unroll
      for (int j=0;j<4;j++) v |= (ull)cvt_bf16(s4[j]*scq) << (16*j);
      st_dev((ull*)whhf + cc, v);
    } else if (c < 90368){
      int cc = c - 90112; int j = cc*2;
      union { float f[2]; ull u; } pv;
      pv.f[0] = bih[j] + bhh[j]; pv.f[1] = bih[j+1] + bhh[j+1];
      st_dev((ull*)bsum + cc, pv.u);
    } else {
      // wf B-fragments: frag = ky*4+kc; cols 0..2 = Wf taps (kx), rest zero
      int cc = c - 90368;
      int i2 = cc*4, frag = i2 >> 9, rem = i2 & 511, ll = rem >> 3, e0 = rem & 7;
      int ky = frag >> 2, kc = frag & 3;
      int n = ll & 15, k0 = kc*32 + ((ll >> 4) << 3) + e0;
      ull v = 0;
      if (n < 3){
        #pragma unroll
        for (int j=0;j<4;j++) v |= (ull)cvt_bf16(Wf[(ky*3 + n)*128 + k0 + j]) << (16*j);
      }
      st_dev((ull*)wfbF + cc, v);
    }
  }
  // zero own export slots (both parities): poll tags always defined
  if (t < 128){
    int p = t >> 6, w2 = t & 63;
    st_dev(expbuf + ((size_t)p*NBLK + blk)*64 + w2, 0);
  }
  __syncthreads();                              // vmcnt drained
  if (t == 0) set_flag(&flags[blk*FSTR], 1);

  // ---- phase H: hid rows y0-2..y0+3 computed redundantly into LDS -------
  {
    int hch = t & 127, g = t >> 7;              // 4 groups over 6 rows
    float wz0[9], wz1[9];
    #pragma unroll
    for (int kk=0;kk<9;kk++){ wz0[kk] = W_hid[(kk*2)*LH + hch];
                              wz1[kk] = W_hid[(kk*2+1)*LH + hch]; }
    float bh = b_hid[hch];
    for (int rr = g; rr < 6; rr += 4){
      int yi = y0 - 2 + rr;
      bool valid = (yi >= 0 && yi < MM);
      for (int x = 0; x < MM; x++){
        float acc2 = 0.f;
        if (valid){
          acc2 = bh;
          #pragma unroll
          for (int ky=0; ky<3; ky++){
            int yy = yi + ky - 1; if (yy < 0 || yy >= MM) continue;
            #pragma unroll
            for (int kx=0; kx<3; kx++){
              int xx = x + kx - 1; if (xx < 0 || xx >= MM) continue;
              int gi = (b*MM + yy)*MM + xx;
              acc2 += mp[gi]*wz0[ky*3+kx] + gl[gi]*wz1[ky*3+kx];
            }
          }
        }
        sH[SIDX(rr, x+1, hch)] = cvt_bf16(acc2);
      }
    }
  }
  if (t < 384){   // zero x-halo columns, rows 0..5
    int k = t >> 6, col = ((t >> 5) & 1) ? 33 : 0, c4 = t & 31;
    *(ull*)&sH[SIDX(k, col, c4*4)] = 0;
  }
  // zero the two never-written tap-scratch entries per product (once)
  if (t < 10){ sCv[t][0][32] = 0.f; sCv[t][2][1] = 0.f; }
  // grid sync: only prepper blocks' flags (blk<=179)
  if (t < 180) wait_flag(&flags[t*FSTR], 1);
  __syncthreads();

  // ---- h0 & c0 convs: rows A..D (128 px), this wave's 16 out-ch ---------
  float c_reg[8][4];        // [mt 0..7 = (row A..D, half)][r]
  {
    floatx4 acch[8], accc[8];
    #pragma unroll
    for (int mt=0;mt<8;mt++){ acch[mt] = (floatx4){0.f,0.f,0.f,0.f};
                              accc[mt] = (floatx4){0.f,0.f,0.f,0.f}; }
    #pragma unroll
    for (int kk=0; kk<9; kk++){
      int ky = kk/3, kx = kk%3;
      #pragma unroll
      for (int kc=0; kc<4; kc++){
        int frag = ((kk*8 + wave)*4 + kc);
        bf16x8 b0 = *(const bf16x8*)(wc0 + (frag << 9) + l*8);
        bf16x8 b1 = *(const bf16x8*)(wc1 + (frag << 9) + l*8);
        #pragma unroll
        for (int mt=0; mt<8; mt++){
          bf16x8 a = *(const bf16x8*)&sH[SIDX((mt>>1)+ky, m16 + (mt&1)*16 + kx, kc*32 + quad*8)];
          acch[mt] = __builtin_amdgcn_mfma_f32_16x16x32_bf16(a, b0, acch[mt], 0,0,0);
          accc[mt] = __builtin_amdgcn_mfma_f32_16x16x32_bf16(a, b1, accc[mt], 0,0,0);
        }
      }
    }
    __syncthreads();                      // all conv reads done
    float bh = b_h0[ch], bc = b_c0[ch];
    #pragma unroll
    for (int mt=0; mt<8; mt++){
      bool dead = (mt < 2 && !hasU) || (mt >= 6 && !hasD);
      #pragma unroll
      for (int r=0; r<4; r++){
        int x = (mt&1)*16 + quad*4 + r;
        float hv = dead ? 0.f : (acch[mt][r] + bh);
        c_reg[mt][r] = dead ? 0.f : (accc[mt][r] + bc);
        sH[SIDX(1+(mt>>1), x+1, ch)] = cvt_bf16(hv);
      }
    }
  }
  __syncthreads();                        // h0 for A..D in LDS rows 1..4

  float wv[4], bs[4];
  #pragma unroll
  for (int q=0;q<4;q++){
    float scq = (q == 2) ? (2.f*L2E) : (-L2E);
    int g = q*128 + ch;
    wv[q] = wih[g]*scq; bs[q] = bsum[g]*scq;
  }
  float bf0 = bfs[0];

  // ---- 15 LSTM steps ----------------------------------------------------
  for (int s = 0; s < NSTEPS; s++){
    int cur = s & 1;
    unsigned tgt = (unsigned)(2 + s);

    // speculative import loads at step start (w5: up-edge, w6: down-edge)
    ull specv = 0; ull* pP = nullptr;
    if (wave == 5 && hasU && l < 32){
      pP = expbuf + ((size_t)cur*NBLK + nU)*64 + 32 + l;  // their DOWN-export
      specv = ld_dev(pP);
    } else if (wave == 6 && hasD && l < 32){
      pP = expbuf + ((size_t)cur*NBLK + nD)*64 + l;       // their UP-export
      specv = ld_dev(pP);
    }

    // P1 (waves 0-4): conv products P(R,ky), 2 per wave. Products feeding
    // exports publish IMMEDIATELY (produced from own rows, no import dep).
    // descriptor: R | ky<<2 | dstRow<<4 | dstPart<<6 | pub<<8 (1=up,2=down)
    if (wave < 5){
      int d0, d1;
      switch (wave){
        case 0:  d0 = 1|(1<<2)|(1<<4)|(1<<6);         d1 = 2|(1<<2)|(2<<4)|(1<<6); break;
        case 1:  d0 = 1|(0<<2)|(2<<4)|(0<<6)|(2<<8);  d1 = 0|(0<<2)|(1<<4)|(0<<6); break;
        case 2:  d0 = 2|(2<<2)|(1<<4)|(2<<6)|(1<<8);  d1 = 3|(2<<2)|(2<<4)|(2<<6); break;
        case 3:  d0 = 0|(1<<2)|(0<<4)|(1<<6);         d1 = 1|(2<<2)|(0<<4)|(2<<6); break;
        default: d0 = 2|(0<<2)|(3<<4)|(0<<6);         d1 = 3|(1<<2)|(3<<4)|(1<<6); break;
      }
      #pragma unroll
      for (int wp = 0; wp < 2; wp++){
        int dsc = wp ? d1 : d0;
        int R = dsc & 3, ky = (dsc>>2)&3, dR = (dsc>>4)&3, dP = (dsc>>6)&3, pub = (dsc>>8)&3;
        int slot = wave*2 + wp;
        floatx4 q0 = (floatx4){0.f,0.f,0.f,0.f};
        floatx4 q1 = (floatx4){0.f,0.f,0.f,0.f};
        #pragma unroll
        for (int kc=0;kc<4;kc++){
          bf16x8 wf = *(const bf16x8*)(wfbF + (((ky*4 + kc) << 9) + l*8));
          bf16x8 aL = *(const bf16x8*)&sH[SIDX(1+R, m16 + 1,  kc*32 + quad*8)];
          bf16x8 aR = *(const bf16x8*)&sH[SIDX(1+R, m16 + 17, kc*32 + quad*8)];
          q0 = __builtin_amdgcn_mfma_f32_16x16x32_bf16(aL, wf, q0, 0,0,0);
          q1 = __builtin_amdgcn_mfma_f32_16x16x32_bf16(aR, wf, q1, 0,0,0);
        }
        if (m16 < 3){
          #pragma unroll
          for (int r=0;r<4;r++){
            sCv[slot][m16][quad*4 + r + m16]      = q0[r];
            sCv[slot][m16][16 + quad*4 + r + m16] = q1[r];
          }
        }
        __asm__ __volatile__("" ::: "memory");  // same-wave DS in-order
        if (l < 32){
          float v = sCv[slot][0][l+1] + sCv[slot][1][l+1] + sCv[slot][2][l+1];
          if (pub){
            bool okp = (pub == 2) ? hasD : hasU;
            if (okp){
              union { float f; unsigned u; } pv; pv.f = v;
              st_dev(expbuf + ((size_t)cur*NBLK + blk)*64 + ((pub == 2) ? 32 : 0) + l,
                     ((ull)tgt << 32) | (ull)pv.u);
            }
          }
          sOwn[dR][dP][l] = v;
        }
      }
    }

    // SINGLE reused accumulator for both GEMM phases (keeps VGPR <= budget)
    ull wa = (ull)whhf;
    asm volatile("" : "+v"(wa));
    const unsigned short* wp8 = (const unsigned short*)wa;
    floatx4 acc[4][4];

    // P2: gates GEMM own rows B,C (LDS rows 2,3); B streamed from L2 whhf
    #pragma unroll
    for (int m=0;m<4;m++)
      #pragma unroll
      for (int q=0;q<4;q++) acc[m][q] = (floatx4){0.f,0.f,0.f,0.f};
    #pragma unroll
    for (int kc=0; kc<4; kc++){
      bf16x8 a0 = *(const bf16x8*)&sH[SIDX(2, m16 + 1,  kc*32 + quad*8)];
      bf16x8 a1 = *(const bf16x8*)&sH[SIDX(2, m16 + 17, kc*32 + quad*8)];
      bf16x8 a2 = *(const bf16x8*)&sH[SIDX(3, m16 + 1,  kc*32 + quad*8)];
      bf16x8 a3 = *(const bf16x8*)&sH[SIDX(3, m16 + 17, kc*32 + quad*8)];
      #pragma unroll
      for (int q=0; q<4; q++){
        bf16x8 bq = *(const bf16x8*)(wp8 + ((q*32 + wave*4 + kc) << 9) + l*8);
        acc[0][q] = __builtin_amdgcn_mfma_f32_16x16x32_bf16(a0, bq, acc[0][q], 0,0,0);
        acc[1][q] = __builtin_amdgcn_mfma_f32_16x16x32_bf16(a1, bq, acc[1][q], 0,0,0);
        acc[2][q] = __builtin_amdgcn_mfma_f32_16x16x32_bf16(a2, bq, acc[2][q], 0,0,0);
        acc[3][q] = __builtin_amdgcn_mfma_f32_16x16x32_bf16(a3, bq, acc[3][q], 0,0,0);
      }
    }
    __syncthreads();                      // B1: sOwn complete, h_s reads of B,C done

    // E1: epilogue own rows B,C -> h_{s+1} into LDS rows 2,3 (no import dep)
    #pragma unroll
    for (int m=0; m<4; m++){
      int mt = 2 + m, rw = 1 + (m>>1);
      #pragma unroll
      for (int r=0; r<4; r++){
        int x = (m&1)*16 + quad*4 + r;
        float iv = ((bf0 + sOwn[rw][0][x]) + sOwn[rw][1][x]) + sOwn[rw][2][x];
        float p0 = acc[m][0][r] + iv*wv[0] + bs[0];
        float p1 = acc[m][1][r] + iv*wv[1] + bs[1];
        float p2 = acc[m][2][r] + iv*wv[2] + bs[2];
        float p3 = acc[m][3][r] + iv*wv[3] + bs[3];
        float ig = frcp(1.f + ex2(p0));
        float fg = frcp(1.f + ex2(p1));
        float gg = 1.f - 2.f*frcp(1.f + ex2(p2));
        float og = frcp(1.f + ex2(p3));
        float cn = fg*c_reg[mt][r] + ig*gg;
        c_reg[mt][r] = cn;
        float th = 1.f - 2.f*frcp(1.f + ex2((2.f*L2E)*cn));
        sH[SIDX(1+rw, x+1, ch)] = cvt_bf16(og*th);
      }
    }

    // P3: gates GEMM halo rows A,D (LDS rows 1,4 — still h_s); acc reused
    #pragma unroll
    for (int m=0;m<4;m++)
      #pragma unroll
      for (int q=0;q<4;q++) acc[m][q] = (floatx4){0.f,0.f,0.f,0.f};
    #pragma unroll
    for (int kc=0; kc<4; kc++){
      bf16x8 a0 = *(const bf16x8*)&sH[SIDX(1, m16 + 1,  kc*32 + quad*8)];
      bf16x8 a1 = *(const bf16x8*)&sH[SIDX(1, m16 + 17, kc*32 + quad*8)];
      bf16x8 a2 = *(const bf16x8*)&sH[SIDX(4, m16 + 1,  kc*32 + quad*8)];
      bf16x8 a3 = *(const bf16x8*)&sH[SIDX(4, m16 + 17, kc*32 + quad*8)];
      #pragma unroll
      for (int q=0; q<4; q++){
        bf16x8 bq = *(const bf16x8*)(wp8 + ((q*32 + wave*4 + kc) << 9) + l*8);
        acc[0][q] = __builtin_amdgcn_mfma_f32_16x16x32_bf16(a0, bq, acc[0][q], 0,0,0);
        acc[1][q] = __builtin_amdgcn_mfma_f32_16x16x32_bf16(a1, bq, acc[1][q], 0,0,0);
        acc[2][q] = __builtin_amdgcn_mfma_f32_16x16x32_bf16(a2, bq, acc[2][q], 0,0,0);
        acc[3][q] = __builtin_amdgcn_mfma_f32_16x16x32_bf16(a3, bq, acc[3][q], 0,0,0);
      }
    }

    // import check/poll (w5/w6) — export has been in flight the whole step
    if (pP){
      ull val = specv;
      if ((int)((unsigned)(val >> 32) - tgt) < 0){
        ull c0 = ld_dev(pP), c1 = ld_dev(pP);
        while ((int)((unsigned)(c0 >> 32) - tgt) < 0){ c0 = c1; c1 = ld_dev(pP); }
        val = c0;
      }
      union { unsigned u; float f; } pv; pv.u = (unsigned)val;
      sImp[(wave == 5) ? 0 : 1][l] = pv.f;
    }
    __syncthreads();                      // B3a: sImp ready, h_s(A,D) reads done

    // E2: halo epilogue rows A,D -> h_{s+1} into LDS rows 1,4
    #pragma unroll
    for (int m=0; m<4; m++){
      int mt = (m < 2) ? m : (4 + m);     // 0,1,6,7
      int rw = (m < 2) ? 0 : 3;
      if ((rw == 0) ? hasU : hasD){
        #pragma unroll
        for (int r=0; r<4; r++){
          int x = (m&1)*16 + quad*4 + r;
          float pa = (rw == 0) ? sImp[0][x] : sOwn[3][0][x];
          float pc = sOwn[rw][1][x];
          float pb = (rw == 0) ? sOwn[0][2][x] : sImp[1][x];
          float iv = ((bf0 + pa) + pc) + pb;
          float p0 = acc[m][0][r] + iv*wv[0] + bs[0];
          float p1 = acc[m][1][r] + iv*wv[1] + bs[1];
          float p2 = acc[m][2][r] + iv*wv[2] + bs[2];
          float p3 = acc[m][3][r] + iv*wv[3] + bs[3];
          float ig = frcp(1.f + ex2(p0));
          float fg = frcp(1.f + ex2(p1));
          float gg = 1.f - 2.f*frcp(1.f + ex2(p2));
          float og = frcp(1.f + ex2(p3));
          float cn = fg*c_reg[mt][r] + ig*gg;
          c_reg[mt][r] = cn;
          float th = 1.f - 2.f*frcp(1.f + ex2((2.f*L2E)*cn));
          sH[SIDX((rw == 0) ? 1 : 4, x+1, ch)] = cvt_bf16(og*th);
        }
      }
    }
    __syncthreads();                      // B3b: all h_{s+1} visible in LDS
  }

  // ---- policy: logits + 4-way softmax from own rows (LDS rows 2,3) ------
  {
    int px = t >> 3, s8 = t & 7;
    int base = SIDX(2+(px>>5), (px&31)+1, s8*16);
    uint4 h0v = *(const uint4*)&sH[base];
    uint4 h1v = *(const uint4*)&sH[base + 8];
    float la[4] = {0.f,0.f,0.f,0.f};
    const unsigned short* hu = (const unsigned short*)&h0v;
    #pragma unroll
    for (int e=0;e<8;e++){
      int c = s8*16 + e; float hv2 = bf2f(hu[e]);
      const float* w4 = wpol + c*4;
      la[0]+=hv2*w4[0]; la[1]+=hv2*w4[1]; la[2]+=hv2*w4[2]; la[3]+=hv2*w4[3];
    }
    hu = (const unsigned short*)&h1v;
    #pragma unroll
    for (int e=0;e<8;e++){
      int c = s8*16 + 8 + e; float hv2 = bf2f(hu[e]);
      const float* w4 = wpol + c*4;
      la[0]+=hv2*w4[0]; la[1]+=hv2*w4[1]; la[2]+=hv2*w4[2]; la[3]+=hv2*w4[3];
    }
    #pragma unroll
    for (int a=0;a<4;a++){
      la[a] += __shfl_xor(la[a], 1, 64);
      la[a] += __shfl_xor(la[a], 2, 64);
      la[a] += __shfl_xor(la[a], 4, 64);
    }
    if (s8 == 0){
      int y = y0 + (px>>5), x = px & 31;
      float m = fmaxf(fmaxf(la[0],la[1]),fmaxf(la[2],la[3]));
      float e[4]; float sum = 0.f;
      #pragma unroll
      for (int a=0;a<4;a++){ e[a]=__expf(la[a]-m); sum+=e[a]; }
      float inv = frcp(sum);
      #pragma unroll
      for (int a=0;a<4;a++){
        int o = ((b*4 + a)*MM + y)*MM + x;
        out[o] = la[a];
        out[65536 + o] = e[a]*inv;
      }
    }
  }
}

extern "C" void kernel_launch(void* const* d_in, const int* in_sizes, int n_in,
                              void* d_out, int out_size, void* d_ws, size_t ws_size,
                              hipStream_t stream){
  const float* mp    = (const float*)d_in[0];
  const float* gl    = (const float*)d_in[1];
  const float* W_hid = (const float*)d_in[2];
  const float* b_hid = (const float*)d_in[3];
  const float* W_h0  = (const float*)d_in[4];
  const float* b_h0  = (const float*)d_in[5];
  const float* W_c0  = (const float*)d_in[6];
  const float* b_c0  = (const float*)d_in[7];
  const float* W_f   = (const float*)d_in[8];
  const float* b_f   = (const float*)d_in[9];
  const float* W_ih  = (const float*)d_in[10];
  const float* b_ih  = (const float*)d_in[11];
  const float* W_hh  = (const float*)d_in[12];
  const float* b_hh  = (const float*)d_in[13];
  const float* W_pol = (const float*)d_in[14];
  float* out = (float*)d_out;

  char* ws = (char*)d_ws;
  unsigned short* whhf  = (unsigned short*)ws;                     // 128 KB
  float*          bsum  = (float*)(ws + (128<<10));                // 4 KB
  unsigned short* wc0   = (unsigned short*)(ws + (132<<10));       // 288 KB
  unsigned short* wc1   = (unsigned short*)(ws + (420<<10));       // 288 KB
  unsigned short* wfbF  = (unsigned short*)(ws + (708<<10));       // 12 KB
  int*            flags = (int*)(ws + (720<<10));                  // 64 KB
  ull*            expbuf= (ull*)(ws + (784<<10));                  // 256 KB

  k_mega<<<NBLK, 512, 0, stream>>>(
      mp, gl, W_hid, b_hid, W_h0, b_h0, W_c0, b_c0, W_f, b_f,
      W_ih, b_ih, W_hh, b_hh, W_pol,
      wc0, wc1, whhf, bsum, wfbF, expbuf, flags, out);
}

// Round 10
// 312.174 us; speedup vs baseline: 1.0033x; 1.0025x over previous
//
#include <hip/hip_runtime.h>

#define MM 32
#define LH 128
#define NSTEPS 15          // K-1
#define SSTR 136
#define NBLK 256           // 2 own rows + 2 halo rows per block, 512 threads
#define FSTR 32
#define SIDX(row,pxi,ch) (((row)*34 + (pxi))*SSTR + (ch))

typedef __bf16  bf16x8  __attribute__((ext_vector_type(8)));
typedef float   floatx4 __attribute__((ext_vector_type(4)));
typedef unsigned long long ull;

#define L2E 1.4426950408889634f

__device__ __forceinline__ float ex2(float x){
#if __has_builtin(__builtin_amdgcn_exp2f)
  return __builtin_amdgcn_exp2f(x);
#else
  float r; asm volatile("v_exp_f32 %0, %1\n\ts_nop 0" : "=v"(r) : "v"(x)); return r;
#endif
}
__device__ __forceinline__ float frcp(float x){ return __builtin_amdgcn_rcpf(x); }

__device__ __forceinline__ unsigned short cvt_bf16(float x){
  __bf16 b = (__bf16)x; unsigned short u; __builtin_memcpy(&u, &b, 2); return u;
}
__device__ __forceinline__ float bf2f(unsigned short u){
  union { unsigned u2; float f; } v; v.u2 = ((unsigned)u) << 16;
  return v.f;
}

// relaxed agent-scope ops (cross-XCD coherent point) — the proven transport
__device__ __forceinline__ void st_dev(ull* p, ull v){
  __hip_atomic_store(p, v, __ATOMIC_RELAXED, __HIP_MEMORY_SCOPE_AGENT);
}
__device__ __forceinline__ ull ld_dev(ull* p){
  return __hip_atomic_load(p, __ATOMIC_RELAXED, __HIP_MEMORY_SCOPE_AGENT);
}
// poison-safe relaxed spin (0xAAAAAAAA == far behind under signed diff)
__device__ __forceinline__ void wait_flag(int* f, int target){
  while ((int)(__hip_atomic_load(f, __ATOMIC_RELAXED, __HIP_MEMORY_SCOPE_AGENT) - target) < 0){
    __builtin_amdgcn_s_sleep(1);
  }
}
__device__ __forceinline__ void set_flag(int* f, int v){
  __hip_atomic_store(f, v, __ATOMIC_RELAXED, __HIP_MEMORY_SCOPE_AGENT);
}

// HALO-1 scheme, register-budget-safe step schedule. Block p (pair = blk&15,
// y0 = pair*2) maintains LSTM state for rows A=y0-1, B=y0, C=y0+1, D=y0+2
// (A,D computed REDUNDANTLY, bit-identical to the owning neighbors: identical
// MFMA sequences and identical above+center+below fp32 add order). Imports
// are only the conv partials at the halo EDGES (rows y0-2, y0+3). Exports are
// produced from OWN rows at step start (no import dependency); imports are
// consumed three phases later — the fabric RT hides under the step's compute.
//
// R7/R8 lesson: 4-row acc[4][4] + c_reg[8][4] exceeded the backend's
// 128-VGPR occupancy budget (62KB LDS -> 4 waves/EU heuristic) => ~12 regs
// spilled/reloaded per thread-step => 83/94 MB scratch FETCH/WRITE, 2.5x
// slower. Fix is STRUCTURAL: one row per GEMM+epilogue phase, single
// acc2[2][4] (32 regs) reused 4x per step; peak live ~115 < 128. 5 barriers
// per step instead of 3 (barriers are noise vs spill traffic).
//
// expbuf[parity][blk][64]: slots 0..31 = UP-export P(C,ky=2) (consumed by
// p-1's halo-D), 32..63 = DOWN-export P(B,ky=0) (consumed by p+1's halo-A).
// Entry = (tag=2+s)<<32 | f32 bits. Parity double-buffer race-free.

#define GEMM_ROW(LR) \
  { _Pragma("unroll") \
    for (int m=0;m<2;m++){ _Pragma("unroll") \
      for (int q=0;q<4;q++) acc2[m][q] = (floatx4){0.f,0.f,0.f,0.f}; } \
    _Pragma("unroll") \
    for (int kc=0; kc<4; kc++){ \
      bf16x8 a0 = *(const bf16x8*)&sH[SIDX(LR, m16 + 1,  kc*32 + quad*8)]; \
      bf16x8 a1 = *(const bf16x8*)&sH[SIDX(LR, m16 + 17, kc*32 + quad*8)]; \
      _Pragma("unroll") \
      for (int q=0; q<4; q++){ \
        bf16x8 bq = *(const bf16x8*)(wp8 + ((q*32 + wave*4 + kc) << 9) + l*8); \
        acc2[0][q] = __builtin_amdgcn_mfma_f32_16x16x32_bf16(a0, bq, acc2[0][q], 0,0,0); \
        acc2[1][q] = __builtin_amdgcn_mfma_f32_16x16x32_bf16(a1, bq, acc2[1][q], 0,0,0); \
      } \
    } }

#define EPI_ROW(LR, CB, PA, PC, PB, EN) \
  if (EN){ \
    _Pragma("unroll") \
    for (int m=0;m<2;m++){ \
      _Pragma("unroll") \
      for (int r=0;r<4;r++){ \
        int x = m*16 + quad*4 + r; \
        float iv = ((bf0 + (PA)[x]) + (PC)[x]) + (PB)[x]; \
        float p0 = acc2[m][0][r] + iv*wv[0] + bs[0]; \
        float p1 = acc2[m][1][r] + iv*wv[1] + bs[1]; \
        float p2 = acc2[m][2][r] + iv*wv[2] + bs[2]; \
        float p3 = acc2[m][3][r] + iv*wv[3] + bs[3]; \
        float ig = frcp(1.f + ex2(p0)); \
        float fg = frcp(1.f + ex2(p1)); \
        float gg = 1.f - 2.f*frcp(1.f + ex2(p2)); \
        float og = frcp(1.f + ex2(p3)); \
        float cn = fg*c_reg[(CB)+m][r] + ig*gg; \
        c_reg[(CB)+m][r] = cn; \
        float th = 1.f - 2.f*frcp(1.f + ex2((2.f*L2E)*cn)); \
        sH[SIDX(LR, x+1, ch)] = cvt_bf16(og*th); \
      } \
    } \
  }

__global__ __launch_bounds__(512, 2) void k_mega(
    const float* __restrict__ mp,   const float* __restrict__ gl,
    const float* __restrict__ W_hid,const float* __restrict__ b_hid,
    const float* __restrict__ W_h0, const float* __restrict__ b_h0,
    const float* __restrict__ W_c0, const float* __restrict__ b_c0,
    const float* __restrict__ Wf,   const float* __restrict__ bfs,
    const float* __restrict__ wih,  const float* __restrict__ bih,
    const float* __restrict__ Whh,  const float* __restrict__ bhh,
    const float* __restrict__ wpol,
    unsigned short* __restrict__ wc0, unsigned short* __restrict__ wc1,
    unsigned short* __restrict__ whhf, float* __restrict__ bsum,
    unsigned short* __restrict__ wfbF,
    ull* __restrict__ expbuf,
    int* __restrict__ flags, float* __restrict__ out)
{
  // sH rows 0..5: prologue = hid rows y0-2..y0+3; steps: rows 1..4 = A..D
  __shared__ __attribute__((aligned(16))) unsigned short sH[6*34*SSTR]; // 55.5 KB
  __shared__ float sCv[10][3][36];    // per-product tap scratch
  __shared__ float sOwn[4][3][32];    // [out row A..D][above,center,below][x]
  __shared__ float sImp[2][32];       // imported edge partials (for A, for D)

  int t = threadIdx.x, blk = blockIdx.x;
  int pair = blk & 15, b = blk >> 4;
  int y0 = pair*2;
  int nU = blk - 1, nD = blk + 1;
  int wave = t >> 6, l = t & 63, m16 = l & 15, quad = l >> 4;
  bool hasU = (pair > 0), hasD = (pair < 15);
  int ch = wave*16 + m16;             // this wave's 16-ch tile

  // ---- phase P: weight prep into fragment-linear bf16 -------------------
  // W_hh rows prescaled per-gate by SC[q] (folds log2e into exp2 args).
  for (int c = blk*512 + t; c < 91904; c += NBLK*512){
    if (c < 73728){
      int which = (c >= 36864) ? 1 : 0;
      int cc = which ? c - 36864 : c;
      int i2 = cc*4, frag = i2 >> 9, rem = i2 & 511, ll = rem >> 3, e0 = rem & 7;
      int kk = frag >> 5, ct = (frag >> 2) & 7, kc = frag & 3;
      int co = ct*16 + (ll & 15), ci0 = kc*32 + ((ll >> 4) << 3) + e0;
      const float* src = which ? W_c0 : W_h0;
      ull v = 0;
      #pragma unroll
      for (int j=0;j<4;j++) v |= (ull)cvt_bf16(src[(kk<<14) + (ci0+j)*128 + co]) << (16*j);
      st_dev((ull*)(which ? wc1 : wc0) + cc, v);
    } else if (c < 90112){
      int cc = c - 73728;
      int i2 = cc*4, frag = i2 >> 9, rem = i2 & 511, ll = rem >> 3, e0 = rem & 7;
      int q = frag >> 5, ct = (frag >> 2) & 7, kc = frag & 3;
      float scq = (q == 2) ? (2.f*L2E) : (-L2E);
      int rw = q*128 + ct*16 + (ll & 15), col = kc*32 + ((ll >> 4) << 3) + e0;
      const float* s4 = Whh + rw*128 + col;
      ull v = 0;
      #pragma unroll
      for (int j=0;j<4;j++) v |= (ull)cvt_bf16(s4[j]*scq) << (16*j);
      st_dev((ull*)whhf + cc, v);
    } else if (c < 90368){
      int cc = c - 90112; int j = cc*2;
      union { float f[2]; ull u; } pv;
      pv.f[0] = bih[j] + bhh[j]; pv.f[1] = bih[j+1] + bhh[j+1];
      st_dev((ull*)bsum + cc, pv.u);
    } else {
      // wf B-fragments: frag = ky*4+kc; cols 0..2 = Wf taps (kx), rest zero
      int cc = c - 90368;
      int i2 = cc*4, frag = i2 >> 9, rem = i2 & 511, ll = rem >> 3, e0 = rem & 7;
      int ky = frag >> 2, kc = frag & 3;
      int n = ll & 15, k0 = kc*32 + ((ll >> 4) << 3) + e0;
      ull v = 0;
      if (n < 3){
        #pragma unroll
        for (int j=0;j<4;j++) v |= (ull)cvt_bf16(Wf[(ky*3 + n)*128 + k0 + j]) << (16*j);
      }
      st_dev((ull*)wfbF + cc, v);
    }
  }
  // zero own export slots (both parities): poll tags always defined
  if (t < 128){
    int p = t >> 6, w2 = t & 63;
    st_dev(expbuf + ((size_t)p*NBLK + blk)*64 + w2, 0);
  }
  __syncthreads();                              // vmcnt drained
  if (t == 0) set_flag(&flags[blk*FSTR], 1);

  // ---- phase H: hid rows y0-2..y0+3 computed redundantly into LDS -------
  {
    int hch = t & 127, g = t >> 7;              // 4 groups over 6 rows
    float wz0[9], wz1[9];
    #pragma unroll
    for (int kk=0;kk<9;kk++){ wz0[kk] = W_hid[(kk*2)*LH + hch];
                              wz1[kk] = W_hid[(kk*2+1)*LH + hch]; }
    float bh = b_hid[hch];
    for (int rr = g; rr < 6; rr += 4){
      int yi = y0 - 2 + rr;
      bool valid = (yi >= 0 && yi < MM);
      for (int x = 0; x < MM; x++){
        float acc2s = 0.f;
        if (valid){
          acc2s = bh;
          #pragma unroll
          for (int ky=0; ky<3; ky++){
            int yy = yi + ky - 1; if (yy < 0 || yy >= MM) continue;
            #pragma unroll
            for (int kx=0; kx<3; kx++){
              int xx = x + kx - 1; if (xx < 0 || xx >= MM) continue;
              int gi = (b*MM + yy)*MM + xx;
              acc2s += mp[gi]*wz0[ky*3+kx] + gl[gi]*wz1[ky*3+kx];
            }
          }
        }
        sH[SIDX(rr, x+1, hch)] = cvt_bf16(acc2s);
      }
    }
  }
  if (t < 384){   // zero x-halo columns, rows 0..5
    int k = t >> 6, col = ((t >> 5) & 1) ? 33 : 0, c4 = t & 31;
    *(ull*)&sH[SIDX(k, col, c4*4)] = 0;
  }
  // zero the two never-written tap-scratch entries per product (once)
  if (t < 10){ sCv[t][0][32] = 0.f; sCv[t][2][1] = 0.f; }
  // grid sync: only prepper blocks' flags (blk<=179)
  if (t < 180) wait_flag(&flags[t*FSTR], 1);
  __syncthreads();

  // ---- h0 & c0 convs: rows A..D (128 px), this wave's 16 out-ch ---------
  float c_reg[8][4];        // [mt 0..7 = (row A..D, half)][r]
  {
    floatx4 acch[8], accc[8];
    #pragma unroll
    for (int mt=0;mt<8;mt++){ acch[mt] = (floatx4){0.f,0.f,0.f,0.f};
                              accc[mt] = (floatx4){0.f,0.f,0.f,0.f}; }
    #pragma unroll
    for (int kk=0; kk<9; kk++){
      int ky = kk/3, kx = kk%3;
      #pragma unroll
      for (int kc=0; kc<4; kc++){
        int frag = ((kk*8 + wave)*4 + kc);
        bf16x8 b0 = *(const bf16x8*)(wc0 + (frag << 9) + l*8);
        bf16x8 b1 = *(const bf16x8*)(wc1 + (frag << 9) + l*8);
        #pragma unroll
        for (int mt=0; mt<8; mt++){
          bf16x8 a = *(const bf16x8*)&sH[SIDX((mt>>1)+ky, m16 + (mt&1)*16 + kx, kc*32 + quad*8)];
          acch[mt] = __builtin_amdgcn_mfma_f32_16x16x32_bf16(a, b0, acch[mt], 0,0,0);
          accc[mt] = __builtin_amdgcn_mfma_f32_16x16x32_bf16(a, b1, accc[mt], 0,0,0);
        }
      }
    }
    __syncthreads();                      // all conv reads done
    float bh = b_h0[ch], bc = b_c0[ch];
    #pragma unroll
    for (int mt=0; mt<8; mt++){
      bool dead = (mt < 2 && !hasU) || (mt >= 6 && !hasD);
      #pragma unroll
      for (int r=0; r<4; r++){
        int x = (mt&1)*16 + quad*4 + r;
        float hv = dead ? 0.f : (acch[mt][r] + bh);
        c_reg[mt][r] = dead ? 0.f : (accc[mt][r] + bc);
        sH[SIDX(1+(mt>>1), x+1, ch)] = cvt_bf16(hv);
      }
    }
  }
  __syncthreads();                        // h0 for A..D in LDS rows 1..4

  float wv[4], bs[4];
  #pragma unroll
  for (int q=0;q<4;q++){
    float scq = (q == 2) ? (2.f*L2E) : (-L2E);
    int g = q*128 + ch;
    wv[q] = wih[g]*scq; bs[q] = bsum[g]*scq;
  }
  float bf0 = bfs[0];

  // ---- 15 LSTM steps ----------------------------------------------------
  for (int s = 0; s < NSTEPS; s++){
    int cur = s & 1;
    unsigned tgt = (unsigned)(2 + s);

    // speculative import loads at step start (w5: up-edge, w6: down-edge)
    ull specv = 0; ull* pP = nullptr;
    if (wave == 5 && hasU && l < 32){
      pP = expbuf + ((size_t)cur*NBLK + nU)*64 + 32 + l;  // their DOWN-export
      specv = ld_dev(pP);
    } else if (wave == 6 && hasD && l < 32){
      pP = expbuf + ((size_t)cur*NBLK + nD)*64 + l;       // their UP-export
      specv = ld_dev(pP);
    }

    // P1 (waves 0-4): conv products P(R,ky), 2 per wave. Products feeding
    // exports publish IMMEDIATELY (produced from own rows, no import dep).
    // descriptor: R | ky<<2 | dstRow<<4 | dstPart<<6 | pub<<8 (1=up,2=down)
    if (wave < 5){
      int d0, d1;
      switch (wave){
        case 0:  d0 = 1|(1<<2)|(1<<4)|(1<<6);         d1 = 2|(1<<2)|(2<<4)|(1<<6); break;
        case 1:  d0 = 1|(0<<2)|(2<<4)|(0<<6)|(2<<8);  d1 = 0|(0<<2)|(1<<4)|(0<<6); break;
        case 2:  d0 = 2|(2<<2)|(1<<4)|(2<<6)|(1<<8);  d1 = 3|(2<<2)|(2<<4)|(2<<6); break;
        case 3:  d0 = 0|(1<<2)|(0<<4)|(1<<6);         d1 = 1|(2<<2)|(0<<4)|(2<<6); break;
        default: d0 = 2|(0<<2)|(3<<4)|(0<<6);         d1 = 3|(1<<2)|(3<<4)|(1<<6); break;
      }
      #pragma unroll
      for (int wp = 0; wp < 2; wp++){
        int dsc = wp ? d1 : d0;
        int R = dsc & 3, ky = (dsc>>2)&3, dR = (dsc>>4)&3, dP = (dsc>>6)&3, pub = (dsc>>8)&3;
        int slot = wave*2 + wp;
        floatx4 q0 = (floatx4){0.f,0.f,0.f,0.f};
        floatx4 q1 = (floatx4){0.f,0.f,0.f,0.f};
        #pragma unroll
        for (int kc=0;kc<4;kc++){
          bf16x8 wf = *(const bf16x8*)(wfbF + (((ky*4 + kc) << 9) + l*8));
          bf16x8 aL = *(const bf16x8*)&sH[SIDX(1+R, m16 + 1,  kc*32 + quad*8)];
          bf16x8 aR = *(const bf16x8*)&sH[SIDX(1+R, m16 + 17, kc*32 + quad*8)];
          q0 = __builtin_amdgcn_mfma_f32_16x16x32_bf16(aL, wf, q0, 0,0,0);
          q1 = __builtin_amdgcn_mfma_f32_16x16x32_bf16(aR, wf, q1, 0,0,0);
        }
        if (m16 < 3){
          #pragma unroll
          for (int r=0;r<4;r++){
            sCv[slot][m16][quad*4 + r + m16]      = q0[r];
            sCv[slot][m16][16 + quad*4 + r + m16] = q1[r];
          }
        }
        __asm__ __volatile__("" ::: "memory");  // same-wave DS in-order
        if (l < 32){
          float v = sCv[slot][0][l+1] + sCv[slot][1][l+1] + sCv[slot][2][l+1];
          if (pub){
            bool okp = (pub == 2) ? hasD : hasU;
            if (okp){
              union { float f; unsigned u; } pv; pv.f = v;
              st_dev(expbuf + ((size_t)cur*NBLK + blk)*64 + ((pub == 2) ? 32 : 0) + l,
                     ((ull)tgt << 32) | (ull)pv.u);
            }
          }
          sOwn[dR][dP][l] = v;
        }
      }
    }

    // single reused acc2[2][4] (32 regs) for all four row phases
    ull wa = (ull)whhf;
    asm volatile("" : "+v"(wa));
    const unsigned short* wp8 = (const unsigned short*)wa;
    floatx4 acc2[2][4];

    // phase B (LDS row 2, c_reg[2..3])
    GEMM_ROW(2)
    __syncthreads();                      // X1: P1 done (sOwn/exports), row-2 reads done
    EPI_ROW(2, 2, sOwn[1][0], sOwn[1][1], sOwn[1][2], true)

    // phase C (LDS row 3, c_reg[4..5])
    GEMM_ROW(3)
    __syncthreads();                      // X2: row-3 reads done
    EPI_ROW(3, 4, sOwn[2][0], sOwn[2][1], sOwn[2][2], true)

    // phase A (LDS row 1, c_reg[0..1]); import finalize rides behind GEMM-A
    GEMM_ROW(1)
    if (pP){
      ull val = specv;
      if ((int)((unsigned)(val >> 32) - tgt) < 0){
        ull c0 = ld_dev(pP), c1 = ld_dev(pP);
        while ((int)((unsigned)(c0 >> 32) - tgt) < 0){ c0 = c1; c1 = ld_dev(pP); }
        val = c0;
      }
      union { unsigned u; float f; } pv; pv.u = (unsigned)val;
      sImp[(wave == 5) ? 0 : 1][l] = pv.f;
    }
    __syncthreads();                      // X3: row-1 reads done, sImp ready
    EPI_ROW(1, 0, sImp[0], sOwn[0][1], sOwn[0][2], hasU)

    // phase D (LDS row 4, c_reg[6..7])
    GEMM_ROW(4)
    __syncthreads();                      // X4: row-4 reads done
    EPI_ROW(4, 6, sOwn[3][0], sOwn[3][1], sImp[1], hasD)

    __syncthreads();                      // X5: all h_{s+1} visible in LDS
  }

  // ---- policy: logits + 4-way softmax from own rows (LDS rows 2,3) ------
  {
    int px = t >> 3, s8 = t & 7;
    int base = SIDX(2+(px>>5), (px&31)+1, s8*16);
    uint4 h0v = *(const uint4*)&sH[base];
    uint4 h1v = *(const uint4*)&sH[base + 8];
    float la[4] = {0.f,0.f,0.f,0.f};
    const unsigned short* hu = (const unsigned short*)&h0v;
    #pragma unroll
    for (int e=0;e<8;e++){
      int c = s8*16 + e; float hv2 = bf2f(hu[e]);
      const float* w4 = wpol + c*4;
      la[0]+=hv2*w4[0]; la[1]+=hv2*w4[1]; la[2]+=hv2*w4[2]; la[3]+=hv2*w4[3];
    }
    hu = (const unsigned short*)&h1v;
    #pragma unroll
    for (int e=0;e<8;e++){
      int c = s8*16 + 8 + e; float hv2 = bf2f(hu[e]);
      const float* w4 = wpol + c*4;
      la[0]+=hv2*w4[0]; la[1]+=hv2*w4[1]; la[2]+=hv2*w4[2]; la[3]+=hv2*w4[3];
    }
    #pragma unroll
    for (int a=0;a<4;a++){
      la[a] += __shfl_xor(la[a], 1, 64);
      la[a] += __shfl_xor(la[a], 2, 64);
      la[a] += __shfl_xor(la[a], 4, 64);
    }
    if (s8 == 0){
      int y = y0 + (px>>5), x = px & 31;
      float m = fmaxf(fmaxf(la[0],la[1]),fmaxf(la[2],la[3]));
      float e[4]; float sum = 0.f;
      #pragma unroll
      for (int a=0;a<4;a++){ e[a]=__expf(la[a]-m); sum+=e[a]; }
      float inv = frcp(sum);
      #pragma unroll
      for (int a=0;a<4;a++){
        int o = ((b*4 + a)*MM + y)*MM + x;
        out[o] = la[a];
        out[65536 + o] = e[a]*inv;
      }
    }
  }
}

extern "C" void kernel_launch(void* const* d_in, const int* in_sizes, int n_in,
                              void* d_out, int out_size, void* d_ws, size_t ws_size,
                              hipStream_t stream){
  const float* mp    = (const float*)d_in[0];
  const float* gl    = (const float*)d_in[1];
  const float* W_hid = (const float*)d_in[2];
  const float* b_hid = (const float*)d_in[3];
  const float* W_h0  = (const float*)d_in[4];
  const float* b_h0  = (const float*)d_in[5];
  const float* W_c0  = (const float*)d_in[6];
  const float* b_c0  = (const float*)d_in[7];
  const float* W_f   = (const float*)d_in[8];
  const float* b_f   = (const float*)d_in[9];
  const float* W_ih  = (const float*)d_in[10];
  const float* b_ih  = (const float*)d_in[11];
  const float* W_hh  = (const float*)d_in[12];
  const float* b_hh  = (const float*)d_in[13];
  const float* W_pol = (const float*)d_in[14];
  float* out = (float*)d_out;

  char* ws = (char*)d_ws;
  unsigned short* whhf  = (unsigned short*)ws;                     // 128 KB
  float*          bsum  = (float*)(ws + (128<<10));                // 4 KB
  unsigned short* wc0   = (unsigned short*)(ws + (132<<10));       // 288 KB
  unsigned short* wc1   = (unsigned short*)(ws + (420<<10));       // 288 KB
  unsigned short* wfbF  = (unsigned short*)(ws + (708<<10));       // 12 KB
  int*            flags = (int*)(ws + (720<<10));                  // 64 KB
  ull*            expbuf= (ull*)(ws + (784<<10));                  // 256 KB

  k_mega<<<NBLK, 512, 0, stream>>>(
      mp, gl, W_hid, b_hid, W_h0, b_h0, W_c0, b_c0, W_f, b_f,
      W_ih, b_ih, W_hh, b_hh, W_pol,
      wc0, wc1, whhf, bsum, wfbF, expbuf, flags, out);
}

// Round 11
// 170.662 us; speedup vs baseline: 1.8353x; 1.8292x over previous
//
#include <hip/hip_runtime.h>

#define MM 32
#define LH 128
#define NSTEPS 15          // K-1
#define SSTR 136
#define NBLK 256           // 2 rows per block, 512 threads (8 waves)
#define FSTR 32
#define SIDX(row,pxi,ch) (((row)*34 + (pxi))*SSTR + (ch))

typedef __bf16  bf16x8  __attribute__((ext_vector_type(8)));
typedef float   floatx4 __attribute__((ext_vector_type(4)));
typedef unsigned long long ull;

#define L2E 1.4426950408889634f

__device__ __forceinline__ float ex2(float x){
#if __has_builtin(__builtin_amdgcn_exp2f)
  return __builtin_amdgcn_exp2f(x);
#else
  float r; asm volatile("v_exp_f32 %0, %1\n\ts_nop 0" : "=v"(r) : "v"(x)); return r;
#endif
}
__device__ __forceinline__ float frcp(float x){ return __builtin_amdgcn_rcpf(x); }

__device__ __forceinline__ unsigned short cvt_bf16(float x){
  __bf16 b = (__bf16)x; unsigned short u; __builtin_memcpy(&u, &b, 2); return u;
}
__device__ __forceinline__ float bf2f(unsigned short u){
  union { unsigned u2; float f; } v; v.u2 = ((unsigned)u) << 16;
  return v.f;
}

// relaxed agent-scope ops (cross-XCD coherent point) — proven transport
__device__ __forceinline__ void st_dev(ull* p, ull v){
  __hip_atomic_store(p, v, __ATOMIC_RELAXED, __HIP_MEMORY_SCOPE_AGENT);
}
__device__ __forceinline__ ull ld_dev(ull* p){
  return __hip_atomic_load(p, __ATOMIC_RELAXED, __HIP_MEMORY_SCOPE_AGENT);
}
// poison-safe relaxed spin (0xAAAAAAAA == far behind under signed diff)
__device__ __forceinline__ void wait_flag(int* f, int target){
  while ((int)(__hip_atomic_load(f, __ATOMIC_RELAXED, __HIP_MEMORY_SCOPE_AGENT) - target) < 0){
    __builtin_amdgcn_s_sleep(1);
  }
}
__device__ __forceinline__ void set_flag(int* f, int v){
  __hip_atomic_store(f, v, __ATOMIC_RELAXED, __HIP_MEMORY_SCOPE_AGENT);
}

// Export buffers: expbuf[parity][blk][64]; slots 0..31 = up-export (conv
// partial for image row y0-1), 32..63 = down-export (row y0+2). Entry packs
// (tag = 2+s)<<32 | f32 bits: tag+payload in one aligned 8B store. Parity
// double-buffer is race-free: producer overwrites parity p at step s+2 only
// after its step-s+1 import, which requires the consumer past its step-s B2.
//
// R10 delta vs the proven 100.2us kernel: wave 7 (idle in P1) issues its two
// pipelined speculative import loads at STEP START, so the first ~900cy
// agent-load RT overlaps P1+GEMM instead of serializing after the GEMM.
// Stale tags are monotone (old step) -> handled by the existing poll loop.
__global__ __launch_bounds__(512, 2) void k_mega(
    const float* __restrict__ mp,   const float* __restrict__ gl,
    const float* __restrict__ W_hid,const float* __restrict__ b_hid,
    const float* __restrict__ W_h0, const float* __restrict__ b_h0,
    const float* __restrict__ W_c0, const float* __restrict__ b_c0,
    const float* __restrict__ Wf,   const float* __restrict__ bfs,
    const float* __restrict__ wih,  const float* __restrict__ bih,
    const float* __restrict__ Whh,  const float* __restrict__ bhh,
    const float* __restrict__ wpol,
    unsigned short* __restrict__ wc0, unsigned short* __restrict__ wc1,
    unsigned short* __restrict__ whhf, float* __restrict__ bsum,
    unsigned short* __restrict__ wfbF,
    ull* __restrict__ expbuf,
    int* __restrict__ flags, float* __restrict__ out)
{
  __shared__ __attribute__((aligned(16))) unsigned short sH[4*34*SSTR]; // 37 KB
  __shared__ float sCv[6][3][36];     // per-role-wave tap scratch
  __shared__ float sOwn[2][2][32];    // [own row 0/1][part A/B][x]
  __shared__ float sImp[2][32];       // imported neighbor partials (row0,row1)

  int t = threadIdx.x, blk = blockIdx.x;
  int pair = blk & 15, b = blk >> 4;  // row-pair index, image index
  int y0 = pair*2;                    // first image row of the pair
  int wave = t >> 6, l = t & 63, m16 = l & 15, quad = l >> 4;
  bool hasU = (pair > 0), hasD = (pair < 15);
  int ch = wave*16 + m16;             // this wave's 16-ch tile

  // ---- phase P: weight prep into fragment-linear bf16 -------------------
  // W_hh rows are prescaled per-gate by SC[q] (folds log2e into exp2 args).
  for (int c = blk*512 + t; c < 91904; c += NBLK*512){
    if (c < 73728){
      int which = (c >= 36864) ? 1 : 0;
      int cc = which ? c - 36864 : c;
      int i2 = cc*4, frag = i2 >> 9, rem = i2 & 511, ll = rem >> 3, e0 = rem & 7;
      int kk = frag >> 5, ct = (frag >> 2) & 7, kc = frag & 3;
      int co = ct*16 + (ll & 15), ci0 = kc*32 + ((ll >> 4) << 3) + e0;
      const float* src = which ? W_c0 : W_h0;
      ull v = 0;
      #pragma unroll
      for (int j=0;j<4;j++) v |= (ull)cvt_bf16(src[(kk<<14) + (ci0+j)*128 + co]) << (16*j);
      st_dev((ull*)(which ? wc1 : wc0) + cc, v);
    } else if (c < 90112){
      int cc = c - 73728;
      int i2 = cc*4, frag = i2 >> 9, rem = i2 & 511, ll = rem >> 3, e0 = rem & 7;
      int q = frag >> 5, ct = (frag >> 2) & 7, kc = frag & 3;
      float scq = (q == 2) ? (2.f*L2E) : (-L2E);
      int rw = q*128 + ct*16 + (ll & 15), col = kc*32 + ((ll >> 4) << 3) + e0;
      const float* s4 = Whh + rw*128 + col;
      ull v = 0;
      #pragma unroll
      for (int j=0;j<4;j++) v |= (ull)cvt_bf16(s4[j]*scq) << (16*j);
      st_dev((ull*)whhf + cc, v);
    } else if (c < 90368){
      int cc = c - 90112; int j = cc*2;
      union { float f[2]; ull u; } pv;
      pv.f[0] = bih[j] + bhh[j]; pv.f[1] = bih[j+1] + bhh[j+1];
      st_dev((ull*)bsum + cc, pv.u);
    } else {
      // wf B-fragments: frag = ky*4+kc; cols 0..2 = Wf taps (kx), rest zero
      int cc = c - 90368;
      int i2 = cc*4, frag = i2 >> 9, rem = i2 & 511, ll = rem >> 3, e0 = rem & 7;
      int ky = frag >> 2, kc = frag & 3;
      int n = ll & 15, k0 = kc*32 + ((ll >> 4) << 3) + e0;
      ull v = 0;
      if (n < 3){
        #pragma unroll
        for (int j=0;j<4;j++) v |= (ull)cvt_bf16(Wf[(ky*3 + n)*128 + k0 + j]) << (16*j);
      }
      st_dev((ull*)wfbF + cc, v);
    }
  }
  // zero own export slots (both parities): poll tags always defined
  if (t < 128){
    int p = t >> 6, w2 = t & 63;
    st_dev(expbuf + ((size_t)p*NBLK + blk)*64 + w2, 0);
  }
  __syncthreads();                              // vmcnt drained
  if (t == 0) set_flag(&flags[blk*FSTR], 1);

  // ---- phase H: hid rows y0-1..y0+2 computed redundantly into LDS -------
  {
    int hch = t & 127, g = t >> 7;              // LDS row g = image row y0-1+g
    float wz0[9], wz1[9];
    #pragma unroll
    for (int kk=0;kk<9;kk++){ wz0[kk] = W_hid[(kk*2)*LH + hch];
                              wz1[kk] = W_hid[(kk*2+1)*LH + hch]; }
    float bh = b_hid[hch];
    int yi = y0 - 1 + g;
    bool valid = (yi >= 0 && yi < MM);
    for (int x = 0; x < MM; x++){
      float acc2 = 0.f;
      if (valid){
        acc2 = bh;
        #pragma unroll
        for (int ky=0; ky<3; ky++){
          int yy = yi + ky - 1; if (yy < 0 || yy >= MM) continue;
          #pragma unroll
          for (int kx=0; kx<3; kx++){
            int xx = x + kx - 1; if (xx < 0 || xx >= MM) continue;
            int gi = (b*MM + yy)*MM + xx;
            acc2 += mp[gi]*wz0[ky*3+kx] + gl[gi]*wz1[ky*3+kx];
          }
        }
      }
      sH[SIDX(g, x+1, hch)] = cvt_bf16(acc2);
    }
  }
  if (t < 256){   // zero x-halo columns, rows 0..3
    int k = t >> 6, col = ((t >> 5) & 1) ? 33 : 0, c4 = t & 31;
    *(ull*)&sH[SIDX(k, col, c4*4)] = 0;
  }
  // zero the two never-written tap-scratch entries per role wave (once)
  if (t < 6){ sCv[t][0][32] = 0.f; sCv[t][2][1] = 0.f; }
  // grid sync: only prepper blocks' flags (blk<=179)
  if (t < 180) wait_flag(&flags[t*FSTR], 1);
  __syncthreads();

  // ---- h0 & c0 convs: 2 rows (64 px), this wave's 16 out-ch -------------
  float c_reg[4][4];        // [mt][r] — persists across all steps
  {
    floatx4 acch[4], accc[4];
    #pragma unroll
    for (int mt=0;mt<4;mt++){ acch[mt] = (floatx4){0.f,0.f,0.f,0.f};
                              accc[mt] = (floatx4){0.f,0.f,0.f,0.f}; }
    #pragma unroll
    for (int kk=0; kk<9; kk++){
      int ky = kk/3, kx = kk%3;
      #pragma unroll
      for (int kc=0; kc<4; kc++){
        int frag = ((kk*8 + wave)*4 + kc);
        bf16x8 b0 = *(const bf16x8*)(wc0 + (frag << 9) + l*8);
        bf16x8 b1 = *(const bf16x8*)(wc1 + (frag << 9) + l*8);
        #pragma unroll
        for (int mt=0; mt<4; mt++){
          bf16x8 a = *(const bf16x8*)&sH[SIDX((mt>>1)+ky, m16 + (mt&1)*16 + kx, kc*32 + quad*8)];
          acch[mt] = __builtin_amdgcn_mfma_f32_16x16x32_bf16(a, b0, acch[mt], 0,0,0);
          accc[mt] = __builtin_amdgcn_mfma_f32_16x16x32_bf16(a, b1, accc[mt], 0,0,0);
        }
      }
    }
    __syncthreads();                      // all conv reads done
    float bh = b_h0[ch], bc = b_c0[ch];
    #pragma unroll
    for (int mt=0; mt<4; mt++)
      #pragma unroll
      for (int r=0; r<4; r++){
        int px = mt*16 + quad*4 + r;      // 0..63
        c_reg[mt][r] = accc[mt][r] + bc;
        sH[SIDX(1+(px>>5), (px&31)+1, ch)] = cvt_bf16(acch[mt][r] + bh);
      }
  }
  __syncthreads();                        // h0 in LDS rows 1,2

  // W_hh^T fragments cached in registers (64 VGPR — budget is 256 at 2 w/EU)
  bf16x8 bfr[4][4];   // [q][kc]
  #pragma unroll
  for (int q=0;q<4;q++)
    #pragma unroll
    for (int kc=0;kc<4;kc++)
      bfr[q][kc] = *(const bf16x8*)(whhf + (((q*32 + wave*4 + kc) << 9)) + l*8);

  // conv role waves 0..5: (ri = input row 0/1, rky = ky tap 0..2)
  // contribution goes to out row rel = ri + 1 - rky:
  //  w0:(0,0)->own1 A  w1:(1,0)->DOWN  w2:(0,1)->own0 A
  //  w3:(1,1)->own1 B  w4:(0,2)->UP    w5:(1,2)->own0 B
  int ri = wave & 1, rky = wave >> 1;
  bf16x8 wfC[4];
  if (wave < 6){
    #pragma unroll
    for (int kc=0;kc<4;kc++)
      wfC[kc] = *(const bf16x8*)(wfbF + (((rky*4 + kc) << 9) + l*8));
  }
  float wv[4], bs[4];
  #pragma unroll
  for (int q=0;q<4;q++){
    float scq = (q == 2) ? (2.f*L2E) : (-L2E);
    int g = q*128 + ch;
    wv[q] = wih[g]*scq; bs[q] = bsum[g]*scq;
  }
  float bf0 = bfs[0];

  // ---- 15 LSTM steps ----------------------------------------------------
  for (int s = 0; s < NSTEPS; s++){
    int cur = s & 1;

    // wave 7: issue 2 pipelined speculative import loads AT STEP START.
    // First agent-RT overlaps P1+GEMM; stale (older-tag) results are
    // resolved by the poll loop after the GEMM. Parity-2 makes the early
    // read harmless (slot holds step s-2 or step s data only).
    ull sp0 = 0, sp1 = 0; ull* pp = nullptr;
    if (wave == 7){
      int d = l >> 5, x = l & 31;
      bool ok = d ? hasD : hasU;
      if (ok){
        pp = expbuf + ((size_t)cur*NBLK + (d ? blk+1 : blk-1))*64 + (d ? 0 : 32) + x;
        sp0 = ld_dev(pp);
        sp1 = ld_dev(pp);
      }
    }

    // P1: role waves compute their conv-row contribution, tap-sum in private
    // LDS scratch, publish/store IMMEDIATELY (no barrier before publish).
    if (wave < 6){
      bool isExp = (wave == 1) || (wave == 4);
      bool doit = !isExp || (wave == 1 ? hasD : hasU);
      if (doit){
        if (isExp) __builtin_amdgcn_s_setprio(1);
        floatx4 p0 = (floatx4){0.f,0.f,0.f,0.f};
        floatx4 p1 = (floatx4){0.f,0.f,0.f,0.f};
        #pragma unroll
        for (int kc=0;kc<4;kc++){
          bf16x8 aL = *(const bf16x8*)&sH[SIDX(1+ri, m16 + 1,  kc*32 + quad*8)];
          bf16x8 aR = *(const bf16x8*)&sH[SIDX(1+ri, m16 + 17, kc*32 + quad*8)];
          p0 = __builtin_amdgcn_mfma_f32_16x16x32_bf16(aL, wfC[kc], p0, 0,0,0);
          p1 = __builtin_amdgcn_mfma_f32_16x16x32_bf16(aR, wfC[kc], p1, 0,0,0);
        }
        // P[px][tap] -> scratch[tap][px+tap]; all taps of out[x] at idx x+1
        if (m16 < 3){
          #pragma unroll
          for (int r=0;r<4;r++){
            sCv[wave][m16][quad*4 + r + m16]      = p0[r];
            sCv[wave][m16][16 + quad*4 + r + m16] = p1[r];
          }
        }
        __asm__ __volatile__("" ::: "memory");  // same-wave DS in-order
        if (l < 32){
          float v = sCv[wave][0][l+1] + sCv[wave][1][l+1] + sCv[wave][2][l+1];
          if (wave == 1 || wave == 4){
            union { float f; unsigned u; } pv; pv.f = v;
            ull pk = ((ull)(unsigned)(2 + s) << 32) | (ull)pv.u;
            st_dev(expbuf + ((size_t)cur*NBLK + blk)*64 + (wave == 1 ? 32 : 0) + l, pk);
          } else if (wave == 0){
            sOwn[1][0][l] = bf0 + v;
          } else if (wave == 2){
            sOwn[0][0][l] = bf0 + v;
          } else if (wave == 3){
            sOwn[1][1][l] = v;
          } else {             // wave 5
            sOwn[0][1][l] = v;
          }
        }
        if (isExp) __builtin_amdgcn_s_setprio(0);
      }
    }

    // gates GEMM on own rows (LDS rows 1,2), B from registers
    floatx4 acc[4][4];    // [mt][q]
    #pragma unroll
    for (int mt=0;mt<4;mt++)
      #pragma unroll
      for (int q=0;q<4;q++) acc[mt][q] = (floatx4){0.f,0.f,0.f,0.f};
    #pragma unroll
    for (int kc=0; kc<4; kc++){
      bf16x8 a[4];
      #pragma unroll
      for (int mt=0;mt<4;mt++)
        a[mt] = *(const bf16x8*)&sH[SIDX(1+(mt>>1), m16 + (mt&1)*16 + 1, kc*32 + quad*8)];
      #pragma unroll
      for (int q=0; q<4; q++)
        #pragma unroll
        for (int mt=0; mt<4; mt++)
          acc[mt][q] = __builtin_amdgcn_mfma_f32_16x16x32_bf16(a[mt], bfr[q][kc], acc[mt][q], 0,0,0);
    }

    // wave 7: finalize imports (both directions in parallel via lane split);
    // the 2 speculative loads have been in flight since step start
    if (wave == 7){
      int d = l >> 5, x = l & 31;
      float v = 0.f;
      if (pp){
        unsigned tgt = (unsigned)(2 + s);
        while ((int)((unsigned)(sp0 >> 32) - tgt) < 0){ sp0 = sp1; sp1 = ld_dev(pp); }
        union { unsigned u; float f; } pv; pv.u = (unsigned)sp0; v = pv.f;
      }
      sImp[d][x] = v;
    }
    __syncthreads();                      // B2: sOwn/sImp final, row reads done

    // LSTM pointwise epilogue (exp2-form, prescaled gates; rcp not IEEE div)
    #pragma unroll
    for (int mt=0; mt<4; mt++){
      int row = mt >> 1;
      #pragma unroll
      for (int r=0; r<4; r++){
        int x = ((mt & 1) << 4) + quad*4 + r;     // px & 31
        float iv = sOwn[row][0][x] + sOwn[row][1][x] + sImp[row][x];
        float p0 = acc[mt][0][r] + iv*wv[0] + bs[0];
        float p1 = acc[mt][1][r] + iv*wv[1] + bs[1];
        float p2 = acc[mt][2][r] + iv*wv[2] + bs[2];
        float p3 = acc[mt][3][r] + iv*wv[3] + bs[3];
        float ig = frcp(1.f + ex2(p0));
        float fg = frcp(1.f + ex2(p1));
        float gg = 1.f - 2.f*frcp(1.f + ex2(p2));
        float og = frcp(1.f + ex2(p3));
        float cn = fg*c_reg[mt][r] + ig*gg;
        c_reg[mt][r] = cn;
        float th = 1.f - 2.f*frcp(1.f + ex2((2.f*L2E)*cn));
        sH[SIDX(1+row, x+1, ch)] = cvt_bf16(og*th);
      }
    }
    __syncthreads();                      // B3: h_{s+1} visible in LDS
  }

  // ---- policy: logits + 4-way softmax from LDS rows 1,2 -----------------
  {
    int px = t >> 3, s8 = t & 7;
    int base = SIDX(1+(px>>5), (px&31)+1, s8*16);
    uint4 h0v = *(const uint4*)&sH[base];
    uint4 h1v = *(const uint4*)&sH[base + 8];
    float la[4] = {0.f,0.f,0.f,0.f};
    const unsigned short* hu = (const unsigned short*)&h0v;
    #pragma unroll
    for (int e=0;e<8;e++){
      int c = s8*16 + e; float hv2 = bf2f(hu[e]);
      const float* w4 = wpol + c*4;
      la[0]+=hv2*w4[0]; la[1]+=hv2*w4[1]; la[2]+=hv2*w4[2]; la[3]+=hv2*w4[3];
    }
    hu = (const unsigned short*)&h1v;
    #pragma unroll
    for (int e=0;e<8;e++){
      int c = s8*16 + 8 + e; float hv2 = bf2f(hu[e]);
      const float* w4 = wpol + c*4;
      la[0]+=hv2*w4[0]; la[1]+=hv2*w4[1]; la[2]+=hv2*w4[2]; la[3]+=hv2*w4[3];
    }
    #pragma unroll
    for (int a=0;a<4;a++){
      la[a] += __shfl_xor(la[a], 1, 64);
      la[a] += __shfl_xor(la[a], 2, 64);
      la[a] += __shfl_xor(la[a], 4, 64);
    }
    if (s8 == 0){
      int y = y0 + (px>>5), x = px & 31;
      float m = fmaxf(fmaxf(la[0],la[1]),fmaxf(la[2],la[3]));
      float e[4]; float sum = 0.f;
      #pragma unroll
      for (int a=0;a<4;a++){ e[a]=__expf(la[a]-m); sum+=e[a]; }
      float inv = frcp(sum);
      #pragma unroll
      for (int a=0;a<4;a++){
        int o = ((b*4 + a)*MM + y)*MM + x;
        out[o] = la[a];
        out[65536 + o] = e[a]*inv;
      }
    }
  }
}

extern "C" void kernel_launch(void* const* d_in, const int* in_sizes, int n_in,
                              void* d_out, int out_size, void* d_ws, size_t ws_size,
                              hipStream_t stream){
  const float* mp    = (const float*)d_in[0];
  const float* gl    = (const float*)d_in[1];
  const float* W_hid = (const float*)d_in[2];
  const float* b_hid = (const float*)d_in[3];
  const float* W_h0  = (const float*)d_in[4];
  const float* b_h0  = (const float*)d_in[5];
  const float* W_c0  = (const float*)d_in[6];
  const float* b_c0  = (const float*)d_in[7];
  const float* W_f   = (const float*)d_in[8];
  const float* b_f   = (const float*)d_in[9];
  const float* W_ih  = (const float*)d_in[10];
  const float* b_ih  = (const float*)d_in[11];
  const float* W_hh  = (const float*)d_in[12];
  const float* b_hh  = (const float*)d_in[13];
  const float* W_pol = (const float*)d_in[14];
  float* out = (float*)d_out;

  char* ws = (char*)d_ws;
  unsigned short* whhf  = (unsigned short*)ws;                     // 128 KB
  float*          bsum  = (float*)(ws + (128<<10));                // 4 KB
  unsigned short* wc0   = (unsigned short*)(ws + (132<<10));       // 288 KB
  unsigned short* wc1   = (unsigned short*)(ws + (420<<10));       // 288 KB
  unsigned short* wfbF  = (unsigned short*)(ws + (708<<10));       // 12 KB
  int*            flags = (int*)(ws + (720<<10));                  // 64 KB
  ull*            expbuf= (ull*)(ws + (784<<10));                  // 256 KB

  k_mega<<<NBLK, 512, 0, stream>>>(
      mp, gl, W_hid, b_hid, W_h0, b_h0, W_c0, b_c0, W_f, b_f,
      W_ih, b_ih, W_hh, b_hh, W_pol,
      wc0, wc1, whhf, bsum, wfbF, expbuf, flags, out);
}